// Round 5
// baseline (891.925 us; speedup 1.0000x reference)
//
#include <hip/hip_runtime.h>
#include <hip/hip_bf16.h>

// ---------------------------------------------------------------------------
// R11 changes vs R10:
//  * scan_k: 8 fdot2 restructured from two 4-deep chains to 8 independent
//    dot2 + 7-add tree (latency-bound at 33% issue; chain was the stall).
//  * attn_flash: q-tile 64 -> 128 (2 sequential 16-row subs per wave sharing
//    one staged K/V tile + per-wave Ps region). Halves staging/barriers/
//    softmax per unit work; grid (16,32) = 512 blocks = exactly 2/CU.
//  * gemm_bt: __launch_bounds__(256,2) -> (256,3): 3 blocks/CU (LDS fits;
//    VGPR cap 170, est. use ~130).
// ---------------------------------------------------------------------------

#define SEQ     2048
#define BATCH   2
#define MROWS   4096      // BATCH*SEQ
#define DMODEL  1024
#define DINNER  2048
#define DFF     4096
#define QKVLD   3072

typedef __attribute__((ext_vector_type(8))) short bf16x8;
typedef __attribute__((ext_vector_type(4))) float f32x4;
typedef __attribute__((ext_vector_type(2))) __fp16 f16x2;

__device__ __forceinline__ unsigned short f2b(float x){
    __hip_bfloat16 h = __float2bfloat16(x);
    return *reinterpret_cast<unsigned short*>(&h);
}
__device__ __forceinline__ float b2f(unsigned short u){
    __hip_bfloat16 h;
    *reinterpret_cast<unsigned short*>(&h) = u;
    return __bfloat162float(h);
}
__device__ __forceinline__ float gelu_f(float v){
    float u = 0.7978845608f*(v + 0.044715f*v*v*v);
    float e = __expf(2.f*u);
    float th = 1.f - 2.f*__builtin_amdgcn_rcpf(e + 1.f);
    return 0.5f*v*(1.f + th);
}
__device__ __forceinline__ void gload16(const unsigned short* g, unsigned short* l){
    __builtin_amdgcn_global_load_lds(
        (const __attribute__((address_space(1))) void*)g,
        (__attribute__((address_space(3))) void*)l, 16, 0, 0);
}
template<int CTRL>
__device__ __forceinline__ float dppf(float x){
    int r = __builtin_amdgcn_mov_dpp(__builtin_bit_cast(int, x), CTRL, 0xf, 0xf, false);
    return __builtin_bit_cast(float, r);
}
template<int CTRL>
__device__ __forceinline__ int dppi(int x){
    return __builtin_amdgcn_mov_dpp(x, CTRL, 0xf, 0xf, false);
}
template<int CTRL>
__device__ __forceinline__ f16x2 dpp_h2(f16x2 x){
    int r = __builtin_amdgcn_mov_dpp(__builtin_bit_cast(int, x), CTRL, 0xf, 0xf, false);
    return __builtin_bit_cast(f16x2, r);
}

#if __has_builtin(__builtin_amdgcn_exp2f)
#define W_SCALE 2.8853900817779268f   /* 2*log2(e): x2 = 2*log2e*s, e^(2s)=2^x2 */
__device__ __forceinline__ float exp_2s(float x){ return __builtin_amdgcn_exp2f(x); }
#else
#define W_SCALE 2.0f
__device__ __forceinline__ float exp_2s(float x){ return __expf(x); }
#endif

__device__ __forceinline__ float hdot2(f16x2 a, f16x2 b, float c){
#if __has_builtin(__builtin_amdgcn_fdot2)
    return __builtin_amdgcn_fdot2(a, b, c, false);
#else
    return c + (float)a[0]*(float)b[0] + (float)a[1]*(float)b[1];
#endif
}

// ---------------- transpose + cast: W (KxN f32) -> Wt (NxK bf16) ----------
__global__ __launch_bounds__(256) void transpose_cast(
    const float* __restrict__ W, unsigned short* __restrict__ Wt, int K, int N)
{
    __shared__ float t[64*65];
    int n0 = blockIdx.x*64, k0 = blockIdx.y*64;
    int c = threadIdx.x & 63, r0 = threadIdx.x >> 6;
    #pragma unroll
    for (int rr = 0; rr < 64; rr += 4)
        t[(rr+r0)*65 + c] = W[(size_t)(k0+rr+r0)*N + n0 + c];
    __syncthreads();
    #pragma unroll
    for (int rr = 0; rr < 64; rr += 4)
        Wt[(size_t)(n0+rr+r0)*K + k0 + c] = f2b(t[c*65 + rr + r0]);
}

// ---------------- concat 3 bias vectors --------------------------------
__global__ __launch_bounds__(256) void concat_bias(
    const float* __restrict__ b0, const float* __restrict__ b1,
    const float* __restrict__ b2, float* __restrict__ o)
{
    int t = blockIdx.x*256 + threadIdx.x;
    float v = (t < 1024) ? b0[t] : (t < 2048 ? b1[t-1024] : b2[t-2048]);
    o[t] = v;
}

// ---------------- layernorm row=1024, f32 in -> bf16 out ------------------
__global__ __launch_bounds__(256) void layernorm_bf16(
    const float* __restrict__ x, const float* __restrict__ g,
    const float* __restrict__ b, unsigned short* __restrict__ out)
{
    int row = blockIdx.x;
    const float4* xr = (const float4*)(x + (size_t)row*DMODEL);
    int tid = threadIdx.x;
    float4 xv = xr[tid];
    float s  = xv.x + xv.y + xv.z + xv.w;
    float ss = xv.x*xv.x + xv.y*xv.y + xv.z*xv.z + xv.w*xv.w;
    #pragma unroll
    for (int d = 32; d > 0; d >>= 1){ s += __shfl_xor(s,d); ss += __shfl_xor(ss,d); }
    __shared__ float sm[8];
    int wv = tid>>6, ln = tid&63;
    if (ln == 0){ sm[wv] = s; sm[4+wv] = ss; }
    __syncthreads();
    s  = sm[0]+sm[1]+sm[2]+sm[3];
    ss = sm[4]+sm[5]+sm[6]+sm[7];
    float mean = s*(1.f/DMODEL);
    float var  = ss*(1.f/DMODEL) - mean*mean;
    float rstd = rsqrtf(var + 1e-5f);
    float4 gv = ((const float4*)g)[tid];
    float4 bv = ((const float4*)b)[tid];
    ushort4 o;
    o.x = f2b((xv.x-mean)*rstd*gv.x + bv.x);
    o.y = f2b((xv.y-mean)*rstd*gv.y + bv.y);
    o.z = f2b((xv.z-mean)*rstd*gv.z + bv.z);
    o.w = f2b((xv.w-mean)*rstd*gv.w + bv.w);
    ((ushort4*)(out + (size_t)row*DMODEL))[tid] = o;
}

// ---------------- GEMM: C[M,N] = act(A[M,K] @ Bt[N,K]^T + bias) (+res) ----
// 128xBN tile, 4 waves (2x2), wave does 64x(BN/2). BK=64. global_load_lds.
template<int BN, int OUT_BF16, int HAS_RES, int ACT>
__global__ __launch_bounds__(256,3) void gemm_bt(
    const unsigned short* __restrict__ A, const unsigned short* __restrict__ Bt,
    const float* __restrict__ bias, const float* __restrict__ res,
    void* __restrict__ outp, int Ndim, int Kdim)
{
    constexpr int NT = BN/32;               // n-tiles per wave
    constexpr int BROWS = BN/32;            // B staging iters per wave (8 rows each)
    __shared__ unsigned short As[128*64];   // unpadded: required by global_load_lds
    __shared__ unsigned short Bs[BN*64];
    int tid = threadIdx.x;
    int lane = tid & 63, wv = tid >> 6;
    int l15 = lane & 15, quad = lane >> 4;
    int m0 = blockIdx.y*128, n0 = blockIdx.x*BN;
    int mo = (wv>>1)*64, no = (wv&1)*(BN/2);
    int rsub = (lane >> 3);          // 0..7
    int cc8  = (lane & 7)*8;         // element col within 64
    f32x4 zz = {0.f,0.f,0.f,0.f};
    f32x4 acc[4][NT];
    #pragma unroll
    for (int i=0;i<4;++i)
      #pragma unroll
      for (int j=0;j<NT;++j) acc[i][j] = zz;

    for (int k0 = 0; k0 < Kdim; k0 += 64){
        const unsigned short* Ab = A  + (size_t)(m0 + wv*32 + rsub)*Kdim + k0 + cc8;
        const unsigned short* Bb = Bt + (size_t)(n0 + wv*(BN/4) + rsub)*Kdim + k0 + cc8;
        #pragma unroll
        for (int i=0;i<4;++i)
            gload16(Ab + (size_t)(i*8)*Kdim, &As[(wv*32 + i*8)*64]);
        #pragma unroll
        for (int i=0;i<BROWS;++i)
            gload16(Bb + (size_t)(i*8)*Kdim, &Bs[(wv*(BN/4) + i*8)*64]);
        __syncthreads();
        #pragma unroll
        for (int kc=0;kc<2;++kc){
            bf16x8 af[4], bfr[NT];
            #pragma unroll
            for (int t=0;t<4;++t)
                af[t]  = *(const bf16x8*)(&As[(mo + t*16 + l15)*64 + kc*32 + quad*8]);
            #pragma unroll
            for (int t=0;t<NT;++t)
                bfr[t] = *(const bf16x8*)(&Bs[(no + t*16 + l15)*64 + kc*32 + quad*8]);
            #pragma unroll
            for (int mt=0;mt<4;++mt)
              #pragma unroll
              for (int nt=0;nt<NT;++nt)
                acc[mt][nt] = __builtin_amdgcn_mfma_f32_16x16x32_bf16(af[mt], bfr[nt], acc[mt][nt], 0,0,0);
        }
        __syncthreads();
    }
    #pragma unroll
    for (int mt=0;mt<4;++mt){
      #pragma unroll
      for (int nt=0;nt<NT;++nt){
        int gn = n0 + no + nt*16 + l15;
        float bval = bias[gn];
        #pragma unroll
        for (int r=0;r<4;++r){
            int gm = m0 + mo + mt*16 + quad*4 + r;
            size_t off = (size_t)gm*Ndim + gn;
            float v = acc[mt][nt][r] + bval;
            if constexpr (HAS_RES) v += res[off];
            if constexpr (ACT == 1) v = gelu_f(v);
            if constexpr (OUT_BF16) ((unsigned short*)outp)[off] = f2b(v);
            else                    ((float*)outp)[off] = v;
        }
      }
    }
}

// ---------------- V pre-transpose: qkv v-slice -> vT[bh][d=64][SEQ] -------
__global__ __launch_bounds__(256) void transpose_v(
    const unsigned short* __restrict__ qkv, unsigned short* __restrict__ vT)
{
    __shared__ unsigned int t[64*33];   // [k-row][d-pair], pad 33 -> conflict-free
    int bh = blockIdx.y;
    int t0 = blockIdx.x*64;
    int tid = threadIdx.x;
    const size_t base = (size_t)(bh>>4)*SEQ*QKVLD + (size_t)(bh&15)*64 + 2*DMODEL;
    #pragma unroll
    for (int i=0;i<2;++i){
        int idx = tid + i*256;          // 0..511
        int r = idx>>3, cc = idx&7;     // k-row 0..63, d-chunk
        uint4 vv = *(const uint4*)(qkv + base + (size_t)(t0+r)*QKVLD + cc*8);
        t[r*33 + cc*4 + 0] = vv.x;
        t[r*33 + cc*4 + 1] = vv.y;
        t[r*33 + cc*4 + 2] = vv.z;
        t[r*33 + cc*4 + 3] = vv.w;
    }
    __syncthreads();
    unsigned short* outb = vT + (size_t)bh*64*SEQ + t0;
    #pragma unroll
    for (int i=0;i<2;++i){
        int idx = tid + i*256;
        int d = idx>>3, cc = idx&7;     // d-row 0..63, k-chunk
        int sh = (d&1)*16, dp = d>>1;
        unsigned int o4[4];
        #pragma unroll
        for (int j2=0;j2<4;++j2){
            unsigned int ua = t[(cc*8 + 2*j2    )*33 + dp];
            unsigned int ub = t[(cc*8 + 2*j2 + 1)*33 + dp];
            unsigned int ha = (ua >> sh) & 0xffff;
            unsigned int hb = (ub >> sh) & 0xffff;
            o4[j2] = ha | (hb << 16);
        }
        *(uint4*)(outb + (size_t)d*SEQ + cc*8) = *(uint4*)o4;
    }
}

// ---------------- flash attention, causal, 16 heads of 64 ------------------
// q/k from fused qkv (row stride QKVLD); v pre-transposed in vT.
// q-tile 128 (wave owns 32 rows = 2 sequential 16-row subs), KV tile 128,
// staged via global_load_lds into UNPADDED LDS with both-sides XOR swizzle.
__device__ __forceinline__ void stage_kv(
    const unsigned short* __restrict__ k, const unsigned short* __restrict__ vTb,
    int t0, unsigned short* Ks, unsigned short* Vt, int wv, int lane)
{
    #pragma unroll
    for (int p=0;p<4;++p){
        int c0 = p*256 + wv*64;         // wave-uniform chunk base
        int c  = c0 + lane;             // this lane's chunk
        int kr = c>>3, kc = (c&7)*8;    // K: row 0..127, col-chunk
        int vr = c>>4, vc = (c&15)*8;   // V: row 0..63,  col-chunk
        gload16(k   + (size_t)(t0+kr)*QKVLD + (kc ^ ((kr&7)<<3)), Ks + c0*8);
        gload16(vTb + (size_t)vr*SEQ + t0 +   (vc ^ ((vr&7)<<3)), Vt + c0*8);
    }
}

__global__ __launch_bounds__(256,2) void attn_flash(
    const unsigned short* __restrict__ qkv, const unsigned short* __restrict__ vT,
    unsigned short* __restrict__ attn)
{
    __shared__ unsigned short Ks[128*64];   // [k][d], unpadded, col-swizzled
    __shared__ unsigned short Vt[64*128];   // [d][k], unpadded, col-swizzled
    __shared__ unsigned short Ps[64*136];   // [q-sub][k], pad 8, per-wave 16 rows
    int bh = blockIdx.y;
    int qt = (int)gridDim.x - 1 - (int)blockIdx.x;   // heavy blocks first
    int q0 = qt*128;
    int tid = threadIdx.x, wv = tid>>6, lane = tid&63;
    int l15 = lane&15, quad = lane>>4;
    int xsw = (l15&7)<<3;                   // read-side XOR (row&7 == l15&7)
    const size_t basei = (size_t)(bh>>4)*SEQ*QKVLD + (size_t)(bh&15)*64;
    const unsigned short* q = qkv + basei;
    const unsigned short* k = qkv + basei + DMODEL;
    const unsigned short* vTb = vT + (size_t)bh*64*SEQ;
    const size_t baseo = (size_t)(bh>>4)*SEQ*DMODEL + (size_t)(bh&15)*64;

    int nkt = qt + 1;   // number of 128-wide kv tiles (causal)

    stage_kv(k, vTb, 0, Ks, Vt, wv, lane);

    // Q fragments directly from global (no LDS round-trip); 2 subs of 16 rows
    bf16x8 aq[2][2];
    #pragma unroll
    for (int s=0;s<2;++s){
        int qr = q0 + wv*32 + s*16 + l15;
        aq[s][0] = *(const bf16x8*)(q + (size_t)qr*QKVLD + quad*8);
        aq[s][1] = *(const bf16x8*)(q + (size_t)qr*QKVLD + 32 + quad*8);
    }

    float m_i[2][4], l_i[2][4];
    f32x4 zz = {0.f,0.f,0.f,0.f};
    f32x4 o[2][4];
    #pragma unroll
    for (int s=0;s<2;++s)
      #pragma unroll
      for (int r=0;r<4;++r){ m_i[s][r] = -__builtin_inff(); l_i[s][r] = 0.f; }
    #pragma unroll
    for (int s=0;s<2;++s)
      #pragma unroll
      for (int d=0;d<4;++d) o[s][d] = zz;

    const float SCL = 0.1803368801111137f;   // 0.125 * log2(e): exp2-domain softmax

    __syncthreads();   // drains gload_lds vmcnt; tile 0 staged

    for (int kt = 0; kt < nkt; ++kt){
        int t0 = kt*128;
        bool diagt = (kt == qt);

        #pragma unroll
        for (int sub=0; sub<2; ++sub){
            // QK^T: 8 sub-tiles of 16 k-cols each
            f32x4 sc[8];
            #pragma unroll
            for (int st=0;st<8;++st){
                bf16x8 b0 = *(const bf16x8*)(&Ks[(st*16+l15)*64 + ((     quad*8) ^ xsw)]);
                bf16x8 b1 = *(const bf16x8*)(&Ks[(st*16+l15)*64 + ((32 + quad*8) ^ xsw)]);
                sc[st] = __builtin_amdgcn_mfma_f32_16x16x32_bf16(aq[sub][0], b0, zz, 0,0,0);
                sc[st] = __builtin_amdgcn_mfma_f32_16x16x32_bf16(aq[sub][1], b1, sc[st], 0,0,0);
            }
            int qrb = q0 + wv*32 + sub*16 + quad*4;
            float mrow[4];
            #pragma unroll
            for (int r=0;r<4;++r) mrow[r] = -__builtin_inff();
            #pragma unroll
            for (int st=0;st<8;++st)
              #pragma unroll
              for (int r=0;r<4;++r){
                float svv = sc[st][r]*SCL;
                if (diagt && (t0 + st*16 + l15 > qrb + r))
                    svv = -__builtin_inff();
                sc[st][r] = svv;
                mrow[r] = fmaxf(mrow[r], svv);
              }
            #pragma unroll
            for (int d=1; d<16; d<<=1)
              #pragma unroll
              for (int r=0;r<4;++r) mrow[r] = fmaxf(mrow[r], __shfl_xor(mrow[r], d));
            float alpha[4], rsum[4];
            #pragma unroll
            for (int r=0;r<4;++r){
                float mn = fmaxf(m_i[sub][r], mrow[r]);
                alpha[r] = exp_2s(m_i[sub][r] - mn);
                m_i[sub][r] = mn;
            }
            #pragma unroll
            for (int st=0;st<8;++st)
              #pragma unroll
              for (int r=0;r<4;++r) sc[st][r] = exp_2s(sc[st][r] - m_i[sub][r]);
            #pragma unroll
            for (int r=0;r<4;++r){
                rsum[r] = ((sc[0][r]+sc[1][r])+(sc[2][r]+sc[3][r]))
                        + ((sc[4][r]+sc[5][r])+(sc[6][r]+sc[7][r]));
            }
            #pragma unroll
            for (int d=1; d<16; d<<=1)
              #pragma unroll
              for (int r=0;r<4;++r) rsum[r] += __shfl_xor(rsum[r], d);
            #pragma unroll
            for (int r=0;r<4;++r) l_i[sub][r] = l_i[sub][r]*alpha[r] + rsum[r];
            // P -> LDS (own wave's 16 rows; per-wave DS ordering, no barrier)
            #pragma unroll
            for (int st=0;st<8;++st)
              #pragma unroll
              for (int r=0;r<4;++r)
                Ps[(wv*16 + quad*4 + r)*136 + st*16 + l15] = f2b(sc[st][r]);
            #pragma unroll
            for (int d=0;d<4;++d)
              #pragma unroll
              for (int r=0;r<4;++r) o[sub][d][r] = o[sub][d][r]*alpha[r];

            // PV: O[q][d] += P[q][0..127] @ V^T[d][0..127]
            bf16x8 ap[4];
            #pragma unroll
            for (int kch=0;kch<4;++kch)
                ap[kch] = *(const bf16x8*)(&Ps[(wv*16 + l15)*136 + kch*32 + quad*8]);
            #pragma unroll
            for (int dtile=0;dtile<4;++dtile){
                #pragma unroll
                for (int kch=0;kch<4;++kch){
                    bf16x8 bv_ = *(const bf16x8*)(&Vt[(dtile*16+l15)*128 + ((kch*32 + quad*8) ^ xsw)]);
                    o[sub][dtile] = __builtin_amdgcn_mfma_f32_16x16x32_bf16(ap[kch], bv_, o[sub][dtile], 0,0,0);
                }
            }
        }

        if (kt + 1 < nkt){
            __syncthreads();                 // all waves done reading tile kt
            stage_kv(k, vTb, t0 + 128, Ks, Vt, wv, lane);
            __syncthreads();                 // drains vmcnt; tile kt+1 staged
        }
    }
    #pragma unroll
    for (int sub=0; sub<2; ++sub)
      #pragma unroll
      for (int r=0;r<4;++r){
        float inv = 1.f/l_i[sub][r];
        int gm = q0 + wv*32 + sub*16 + quad*4 + r;
        #pragma unroll
        for (int dtile=0;dtile<4;++dtile)
            attn[baseo + (size_t)gm*DMODEL + dtile*16 + l15] = f2b(o[sub][dtile][r]*inv);
      }
}

// ---------------- depthwise causal conv(4) + bias + silu -------------------
__global__ __launch_bounds__(256) void conv_silu(
    const unsigned short* __restrict__ xr, const float* __restrict__ cw,
    const float* __restrict__ cb, unsigned short* __restrict__ xm2)
{
    int idx = blockIdx.x*256 + threadIdx.x;
    int r  = idx >> 10;
    int c2 = (idx & 1023)*2;
    int s  = r & (SEQ-1);
    float4 w0 = *(const float4*)(cw + c2*4);
    float4 w1 = *(const float4*)(cw + (c2+1)*4);
    float w0a[4] = {w0.x,w0.y,w0.z,w0.w};
    float w1a[4] = {w1.x,w1.y,w1.z,w1.w};
    float a0 = cb[c2], a1 = cb[c2+1];
    const unsigned short* xrow = xr + (size_t)r*DFF + c2;
    #pragma unroll
    for (int j=0;j<4;++j){
        int sp = s - 3 + j;
        if (sp >= 0){
            int off = (j-3)*DFF;
            unsigned int u = *(const unsigned int*)(xrow + off);
            a0 += w0a[j]*b2f(u & 0xffff);
            a1 += w1a[j]*b2f(u >> 16);
        }
    }
    float s0 = a0 * __builtin_amdgcn_rcpf(1.f + __expf(-a0));
    float s1 = a1 * __builtin_amdgcn_rcpf(1.f + __expf(-a1));
    unsigned int op = (unsigned int)f2b(s0) | ((unsigned int)f2b(s1) << 16);
    *(unsigned int*)(xm2 + (size_t)r*DINNER + c2) = op;
}

// ---------------- xdbl = xm2 @ xp_w + xp_b, written as {b,c} pairs ---------
__global__ __launch_bounds__(256) void xp_gemm(
    const unsigned short* __restrict__ xm2, const float* __restrict__ w,
    const float* __restrict__ bias, float* __restrict__ xdbl)
{
    int tid = threadIdx.x;
    int lr = tid >> 5, n = tid & 31;
    int row = blockIdx.x*8 + lr;
    const unsigned short* ar = xm2 + (size_t)row*DINNER;
    float acc = bias[n];
    #pragma unroll 4
    for (int k2 = 0; k2 < DINNER; k2 += 2){
        unsigned int u = *(const unsigned int*)(ar + k2);
        acc += b2f(u & 0xffff)*w[k2*32 + n] + b2f(u >> 16)*w[(k2+1)*32 + n];
    }
    int nc = (n < 16) ? 2*n : 2*(n-16)+1;   // interleave: {b_i,c_i} adjacent
    xdbl[(size_t)row*32 + nc] = acc;
}

// ---------------- sequential scan: packed-f16 dot2 + register bc banks -----
// h_{t+1}[i] = tanh(sum_j exp(dtp*A[i][j]) h_t[j]) + b_t[i]*h_t[i] + c_t[i]
// Weights pre-scaled by 2*log2e: x2 = sum (W') h, e^(2s) = exp2(x2),
// tanh = 1 - 2/(e^(2s)+1); h' = fma(-2, rcp(e2+1), (b*h + c + 1)).
// 8 independent dot2 + 7-add tree (shorter dependent chain than 2x4 chains).
__device__ __forceinline__ float scan_step_dot(float h, const f16x2 (&Wp)[8],
                                               float bv, float cv)
{
    float rr = dppf<0x121>(h);
    f16x2 p0 = __builtin_amdgcn_cvt_pkrtz(h, rr);
    f16x2 p1 = dpp_h2<0x122>(p0);
    f16x2 p2 = dpp_h2<0x124>(p0);
    f16x2 p3 = dpp_h2<0x126>(p0);
    f16x2 p4 = dpp_h2<0x128>(p0);
    f16x2 p5 = dpp_h2<0x12a>(p0);
    f16x2 p6 = dpp_h2<0x12c>(p0);
    f16x2 p7 = dpp_h2<0x12e>(p0);
    float d0 = hdot2(Wp[0], p0, 0.f);
    float d1 = hdot2(Wp[1], p1, 0.f);
    float d2 = hdot2(Wp[2], p2, 0.f);
    float d3 = hdot2(Wp[3], p3, 0.f);
    float d4 = hdot2(Wp[4], p4, 0.f);
    float d5 = hdot2(Wp[5], p5, 0.f);
    float d6 = hdot2(Wp[6], p6, 0.f);
    float d7 = hdot2(Wp[7], p7, 0.f);
    float x  = ((d0+d1)+(d2+d3)) + ((d4+d5)+(d6+d7));
    float u  = fmaf(bv, h, cv + 1.f);          // off critical path
    float e2 = exp_2s(x);
    float r  = __builtin_amdgcn_rcpf(e2 + 1.f);
    return fmaf(-2.f, r, u);
}

__device__ __forceinline__ void load_bank(float2 (&bk)[16], const float* src){
    #pragma unroll
    for (int j=0;j<16;++j) bk[j] = *(const float2*)(src + (size_t)j*32);
}

__device__ __forceinline__ void compute16(const float2 (&bk)[16],
                                          const f16x2 (&Wf)[16][8],
                                          float& hn, float* hp, int lane)
{
    float h0s=0.f, h1s=0.f, h2s=0.f;
    #pragma unroll
    for (int j=0;j<16;++j){
        // global t = blk*16 + j -> phase t%16 == j (static weight index)
        hn = scan_step_dot(hn, Wf[j], bk[j].x, bk[j].y);
        if ((j&3)==0)      h0s = hn;
        else if ((j&3)==1) h1s = hn;
        else if ((j&3)==2) h2s = hn;
        else if (lane < 16){
            float4 o4 = {h0s, h1s, h2s, hn};
            *(float4*)(hp + j - 3) = o4;
        }
    }
}

__global__ __launch_bounds__(128,1) void scan_k(
    const float* __restrict__ xdbl, const float* __restrict__ dt,
    const float* __restrict__ A, float* __restrict__ hsT)
{
    int tid = threadIdx.x;
    int lane = tid & 63;
    int b = tid >> 6;
    int i = lane & 15;

    // probe: identical DPP fan applied to lane index -> actual source lanes.
    // pair j of the packed fan covers sources (sj[j], tj[j]).
    int c1 = dppi<0x121>(i);
    int sj[8], tj[8];
    sj[0] = i;               tj[0] = c1;
    sj[1] = dppi<0x122>(i);  tj[1] = dppi<0x122>(c1);
    sj[2] = dppi<0x124>(i);  tj[2] = dppi<0x124>(c1);
    sj[3] = dppi<0x126>(i);  tj[3] = dppi<0x126>(c1);
    sj[4] = dppi<0x128>(i);  tj[4] = dppi<0x128>(c1);
    sj[5] = dppi<0x12a>(i);  tj[5] = dppi<0x12a>(c1);
    sj[6] = dppi<0x12c>(i);  tj[6] = dppi<0x12c>(c1);
    sj[7] = dppi<0x12e>(i);  tj[7] = dppi<0x12e>(c1);

    // packed-f16 weight table: 16 phases x 8 pairs = 128 VGPRs
    f16x2 Wf[16][8];
    #pragma unroll
    for (int p=0;p<16;++p){
        float dtp = __expf(dt[p]);
        #pragma unroll
        for (int jj=0;jj<8;++jj){
            float w0 = W_SCALE*__expf(dtp * A[i*16 + sj[jj]]);
            float w1 = W_SCALE*__expf(dtp * A[i*16 + tj[jj]]);
            Wf[p][jj] = __builtin_amdgcn_cvt_pkrtz(w0, w1);
        }
    }

    // b/c stream: global -> 2x16 float2 register banks, 16-step prefetch lead
    const float* src = xdbl + (size_t)(b*SEQ)*32 + 2*i;
    float* hp = hsT + (size_t)(b*16 + i)*SEQ;
    float2 bA[16], bB[16];
    load_bank(bA, src);
    float hn = 0.f;
    for (int bp = 0; bp < 64; ++bp){
        int t0 = bp*32;
        load_bank(bB, src + (size_t)(t0+16)*32);
        compute16(bA, Wf, hn, hp + t0, lane);
        int t2 = (bp < 63) ? (t0 + 32) : 0;      // last iter: dummy reload of blk 0
        load_bank(bA, src + (size_t)t2*32);
        compute16(bB, Wf, hn, hp + t0 + 16, lane);
    }
}

// ---------------- y = repeat(hsT,128) + res (bf16) -------------------------
__global__ __launch_bounds__(256) void y_assemble(
    const float* __restrict__ hsT, const unsigned short* __restrict__ xr,
    unsigned short* __restrict__ y)
{
    int idx = blockIdx.x*256 + threadIdx.x;
    int r = idx >> 10;
    int c2 = (idx & 1023)*2;
    int bb = r >> 11, s = r & (SEQ-1);
    unsigned int u = *(const unsigned int*)(xr + (size_t)r*DFF + DINNER + c2);
    float h0 = hsT[(size_t)(bb*16 + (c2 >> 7))*SEQ + s];
    float y0 = h0 + b2f(u & 0xffff);
    float y1 = h0 + b2f(u >> 16);
    *(unsigned int*)(y + (size_t)r*DINNER + c2) =
        (unsigned int)f2b(y0) | ((unsigned int)f2b(y1) << 16);
}

// ---------------------------------------------------------------------------
extern "C" void kernel_launch(void* const* d_in, const int* in_sizes, int n_in,
                              void* d_out, int out_size, void* d_ws, size_t ws_size,
                              hipStream_t stream)
{
    (void)in_sizes; (void)n_in; (void)out_size; (void)ws_size;
    const float* x     = (const float*)d_in[0];
    const float* ln1_g = (const float*)d_in[1];
    const float* ln1_b = (const float*)d_in[2];
    const float* Wq    = (const float*)d_in[3];
    const float* bq    = (const float*)d_in[4];
    const float* Wk    = (const float*)d_in[5];
    const float* bk    = (const float*)d_in[6];
    const float* Wv    = (const float*)d_in[7];
    const float* bv    = (const float*)d_in[8];
    const float* Wo    = (const float*)d_in[9];
    const float* bo    = (const float*)d_in[10];
    const float* ln2_g = (const float*)d_in[11];
    const float* ln2_b = (const float*)d_in[12];
    const float* in_w  = (const float*)d_in[13];
    const float* in_b  = (const float*)d_in[14];
    const float* conv_w= (const float*)d_in[15];
    const float* conv_b= (const float*)d_in[16];
    const float* xp_w  = (const float*)d_in[17];
    const float* xp_b  = (const float*)d_in[18];
    const float* dt    = (const float*)d_in[19];
    const float* A     = (const float*)d_in[20];
    const float* out_w = (const float*)d_in[22];
    const float* out_b = (const float*)d_in[23];
    const float* ln3_g = (const float*)d_in[24];
    const float* ln3_b = (const float*)d_in[25];
    const float* fc1_w = (const float*)d_in[26];
    const float* fc1_b = (const float*)d_in[27];
    const float* fc2_w = (const float*)d_in[28];
    const float* fc2_b = (const float*)d_in[29];

    char* ws = (char*)d_ws;
    const size_t MB = 1ull << 20;
    unsigned short* qkvT = (unsigned short*)(ws + 0*MB);   // WqT|WkT|WvT, 6MB
    unsigned short* WoT  = (unsigned short*)(ws + 6*MB);
    unsigned short* inT  = (unsigned short*)(ws + 8*MB);
    unsigned short* outT = (unsigned short*)(ws + 16*MB);
    unsigned short* f1T  = (unsigned short*)(ws + 20*MB);
    unsigned short* f2T  = (unsigned short*)(ws + 28*MB);
    unsigned short* hbf  = (unsigned short*)(ws + 36*MB);  // also vT window
    float*          x2   = (float*)(ws + 44*MB);
    float*          x3   = (float*)(ws + 60*MB);
    unsigned short* qkv  = (unsigned short*)(ws + 76*MB);  // 24MB fused QKV
    unsigned short* attnb= (unsigned short*)(ws + 100*MB);
    unsigned short* xr   = (unsigned short*)(ws + 76*MB);  // reuse after attn
    unsigned short* ffn  = (unsigned short*)(ws + 76*MB);  // reuse after y
    unsigned short* xm2  = (unsigned short*)(ws + 108*MB);
    unsigned short* yb   = (unsigned short*)(ws + 108*MB); // reuse after xp
    float*          xdbl = (float*)(ws + 124*MB);
    float*          hsb  = (float*)(ws + 124*MB + 512*1024);
    float*          bqkv = (float*)(ws + 125*MB);

    dim3 blk(256);
    transpose_cast<<<dim3(16,16), blk, 0, stream>>>(Wq, qkvT,              1024, 1024);
    transpose_cast<<<dim3(16,16), blk, 0, stream>>>(Wk, qkvT + 1024*1024,  1024, 1024);
    transpose_cast<<<dim3(16,16), blk, 0, stream>>>(Wv, qkvT + 2*1024*1024,1024, 1024);
    transpose_cast<<<dim3(16,16), blk, 0, stream>>>(Wo, WoT, 1024, 1024);
    transpose_cast<<<dim3(64,16), blk, 0, stream>>>(in_w, inT, 1024, 4096);
    transpose_cast<<<dim3(16,32), blk, 0, stream>>>(out_w, outT, 2048, 1024);
    transpose_cast<<<dim3(64,16), blk, 0, stream>>>(fc1_w, f1T, 1024, 4096);
    transpose_cast<<<dim3(16,64), blk, 0, stream>>>(fc2_w, f2T, 4096, 1024);
    concat_bias<<<12, blk, 0, stream>>>(bq, bk, bv, bqkv);

    layernorm_bf16<<<MROWS, blk, 0, stream>>>(x, ln1_g, ln1_b, hbf);
    gemm_bt<128,1,0,0><<<dim3(24,32), blk, 0, stream>>>(hbf, qkvT, bqkv, nullptr, qkv, QKVLD, 1024);
    transpose_v<<<dim3(32,32), blk, 0, stream>>>(qkv, hbf);   // vT in hbf window
    attn_flash<<<dim3(16,32), blk, 0, stream>>>(qkv, hbf, attnb);
    gemm_bt<64,0,1,0><<<dim3(16,32), blk, 0, stream>>>(attnb, WoT, bo, x, x2, 1024, 1024);
    layernorm_bf16<<<MROWS, blk, 0, stream>>>(x2, ln2_g, ln2_b, hbf);
    gemm_bt<128,1,0,0><<<dim3(32,32), blk, 0, stream>>>(hbf, inT, in_b, nullptr, xr, 4096, 1024);
    conv_silu<<<16384, blk, 0, stream>>>(xr, conv_w, conv_b, xm2);
    xp_gemm<<<512, blk, 0, stream>>>(xm2, xp_w, xp_b, xdbl);
    scan_k<<<1, dim3(128), 0, stream>>>(xdbl, dt, A, hsb);
    y_assemble<<<16384, blk, 0, stream>>>(hsb, xr, yb);
    gemm_bt<64,0,1,0><<<dim3(16,32), blk, 0, stream>>>(yb, outT, out_b, x2, x3, 1024, 2048);
    layernorm_bf16<<<MROWS, blk, 0, stream>>>(x3, ln3_g, ln3_b, hbf);
    gemm_bt<128,1,0,1><<<dim3(32,32), blk, 0, stream>>>(hbf, f1T, fc1_b, nullptr, ffn, 4096, 1024);
    gemm_bt<64,0,1,0><<<dim3(16,32), blk, 0, stream>>>(ffn, f2T, fc2_b, x3, (float*)d_out, 1024, 4096);
}

// Round 6
// 859.651 us; speedup vs baseline: 1.0375x; 1.0375x over previous
//
#include <hip/hip_runtime.h>
#include <hip/hip_bf16.h>

// ---------------------------------------------------------------------------
// R12 changes vs R11:
//  * scan_step_dot REVERTED to the R10 chained 2x4 fdot2 form (measured
//    141us). R11's 8-indep + 7-add tree regressed 141->208: chained dot2
//    gets the accumulate free in-instruction; a 1-wave/SIMD kernel pays for
//    every extra issued op. Lesson recorded.
//  * xp_gemm writes c+1 for the c-columns; scan's u = fma(b,h,cv) absorbs
//    the former "+1.f" (one fewer VALU op per scan step).
//  * attn_flash q-tile 128 and gemm_bt (256,3) kept from R11 (-38us).
// ---------------------------------------------------------------------------

#define SEQ     2048
#define BATCH   2
#define MROWS   4096      // BATCH*SEQ
#define DMODEL  1024
#define DINNER  2048
#define DFF     4096
#define QKVLD   3072

typedef __attribute__((ext_vector_type(8))) short bf16x8;
typedef __attribute__((ext_vector_type(4))) float f32x4;
typedef __attribute__((ext_vector_type(2))) __fp16 f16x2;

__device__ __forceinline__ unsigned short f2b(float x){
    __hip_bfloat16 h = __float2bfloat16(x);
    return *reinterpret_cast<unsigned short*>(&h);
}
__device__ __forceinline__ float b2f(unsigned short u){
    __hip_bfloat16 h;
    *reinterpret_cast<unsigned short*>(&h) = u;
    return __bfloat162float(h);
}
__device__ __forceinline__ float gelu_f(float v){
    float u = 0.7978845608f*(v + 0.044715f*v*v*v);
    float e = __expf(2.f*u);
    float th = 1.f - 2.f*__builtin_amdgcn_rcpf(e + 1.f);
    return 0.5f*v*(1.f + th);
}
__device__ __forceinline__ void gload16(const unsigned short* g, unsigned short* l){
    __builtin_amdgcn_global_load_lds(
        (const __attribute__((address_space(1))) void*)g,
        (__attribute__((address_space(3))) void*)l, 16, 0, 0);
}
template<int CTRL>
__device__ __forceinline__ float dppf(float x){
    int r = __builtin_amdgcn_mov_dpp(__builtin_bit_cast(int, x), CTRL, 0xf, 0xf, false);
    return __builtin_bit_cast(float, r);
}
template<int CTRL>
__device__ __forceinline__ int dppi(int x){
    return __builtin_amdgcn_mov_dpp(x, CTRL, 0xf, 0xf, false);
}
template<int CTRL>
__device__ __forceinline__ f16x2 dpp_h2(f16x2 x){
    int r = __builtin_amdgcn_mov_dpp(__builtin_bit_cast(int, x), CTRL, 0xf, 0xf, false);
    return __builtin_bit_cast(f16x2, r);
}

#if __has_builtin(__builtin_amdgcn_exp2f)
#define W_SCALE 2.8853900817779268f   /* 2*log2(e): x2 = 2*log2e*s, e^(2s)=2^x2 */
__device__ __forceinline__ float exp_2s(float x){ return __builtin_amdgcn_exp2f(x); }
#else
#define W_SCALE 2.0f
__device__ __forceinline__ float exp_2s(float x){ return __expf(x); }
#endif

__device__ __forceinline__ float hdot2(f16x2 a, f16x2 b, float c){
#if __has_builtin(__builtin_amdgcn_fdot2)
    return __builtin_amdgcn_fdot2(a, b, c, false);
#else
    return c + (float)a[0]*(float)b[0] + (float)a[1]*(float)b[1];
#endif
}

// ---------------- transpose + cast: W (KxN f32) -> Wt (NxK bf16) ----------
__global__ __launch_bounds__(256) void transpose_cast(
    const float* __restrict__ W, unsigned short* __restrict__ Wt, int K, int N)
{
    __shared__ float t[64*65];
    int n0 = blockIdx.x*64, k0 = blockIdx.y*64;
    int c = threadIdx.x & 63, r0 = threadIdx.x >> 6;
    #pragma unroll
    for (int rr = 0; rr < 64; rr += 4)
        t[(rr+r0)*65 + c] = W[(size_t)(k0+rr+r0)*N + n0 + c];
    __syncthreads();
    #pragma unroll
    for (int rr = 0; rr < 64; rr += 4)
        Wt[(size_t)(n0+rr+r0)*K + k0 + c] = f2b(t[c*65 + rr + r0]);
}

// ---------------- concat 3 bias vectors --------------------------------
__global__ __launch_bounds__(256) void concat_bias(
    const float* __restrict__ b0, const float* __restrict__ b1,
    const float* __restrict__ b2, float* __restrict__ o)
{
    int t = blockIdx.x*256 + threadIdx.x;
    float v = (t < 1024) ? b0[t] : (t < 2048 ? b1[t-1024] : b2[t-2048]);
    o[t] = v;
}

// ---------------- layernorm row=1024, f32 in -> bf16 out ------------------
__global__ __launch_bounds__(256) void layernorm_bf16(
    const float* __restrict__ x, const float* __restrict__ g,
    const float* __restrict__ b, unsigned short* __restrict__ out)
{
    int row = blockIdx.x;
    const float4* xr = (const float4*)(x + (size_t)row*DMODEL);
    int tid = threadIdx.x;
    float4 xv = xr[tid];
    float s  = xv.x + xv.y + xv.z + xv.w;
    float ss = xv.x*xv.x + xv.y*xv.y + xv.z*xv.z + xv.w*xv.w;
    #pragma unroll
    for (int d = 32; d > 0; d >>= 1){ s += __shfl_xor(s,d); ss += __shfl_xor(ss,d); }
    __shared__ float sm[8];
    int wv = tid>>6, ln = tid&63;
    if (ln == 0){ sm[wv] = s; sm[4+wv] = ss; }
    __syncthreads();
    s  = sm[0]+sm[1]+sm[2]+sm[3];
    ss = sm[4]+sm[5]+sm[6]+sm[7];
    float mean = s*(1.f/DMODEL);
    float var  = ss*(1.f/DMODEL) - mean*mean;
    float rstd = rsqrtf(var + 1e-5f);
    float4 gv = ((const float4*)g)[tid];
    float4 bv = ((const float4*)b)[tid];
    ushort4 o;
    o.x = f2b((xv.x-mean)*rstd*gv.x + bv.x);
    o.y = f2b((xv.y-mean)*rstd*gv.y + bv.y);
    o.z = f2b((xv.z-mean)*rstd*gv.z + bv.z);
    o.w = f2b((xv.w-mean)*rstd*gv.w + bv.w);
    ((ushort4*)(out + (size_t)row*DMODEL))[tid] = o;
}

// ---------------- GEMM: C[M,N] = act(A[M,K] @ Bt[N,K]^T + bias) (+res) ----
// 128xBN tile, 4 waves (2x2), wave does 64x(BN/2). BK=64. global_load_lds.
template<int BN, int OUT_BF16, int HAS_RES, int ACT>
__global__ __launch_bounds__(256,3) void gemm_bt(
    const unsigned short* __restrict__ A, const unsigned short* __restrict__ Bt,
    const float* __restrict__ bias, const float* __restrict__ res,
    void* __restrict__ outp, int Ndim, int Kdim)
{
    constexpr int NT = BN/32;               // n-tiles per wave
    constexpr int BROWS = BN/32;            // B staging iters per wave (8 rows each)
    __shared__ unsigned short As[128*64];   // unpadded: required by global_load_lds
    __shared__ unsigned short Bs[BN*64];
    int tid = threadIdx.x;
    int lane = tid & 63, wv = tid >> 6;
    int l15 = lane & 15, quad = lane >> 4;
    int m0 = blockIdx.y*128, n0 = blockIdx.x*BN;
    int mo = (wv>>1)*64, no = (wv&1)*(BN/2);
    int rsub = (lane >> 3);          // 0..7
    int cc8  = (lane & 7)*8;         // element col within 64
    f32x4 zz = {0.f,0.f,0.f,0.f};
    f32x4 acc[4][NT];
    #pragma unroll
    for (int i=0;i<4;++i)
      #pragma unroll
      for (int j=0;j<NT;++j) acc[i][j] = zz;

    for (int k0 = 0; k0 < Kdim; k0 += 64){
        const unsigned short* Ab = A  + (size_t)(m0 + wv*32 + rsub)*Kdim + k0 + cc8;
        const unsigned short* Bb = Bt + (size_t)(n0 + wv*(BN/4) + rsub)*Kdim + k0 + cc8;
        #pragma unroll
        for (int i=0;i<4;++i)
            gload16(Ab + (size_t)(i*8)*Kdim, &As[(wv*32 + i*8)*64]);
        #pragma unroll
        for (int i=0;i<BROWS;++i)
            gload16(Bb + (size_t)(i*8)*Kdim, &Bs[(wv*(BN/4) + i*8)*64]);
        __syncthreads();
        #pragma unroll
        for (int kc=0;kc<2;++kc){
            bf16x8 af[4], bfr[NT];
            #pragma unroll
            for (int t=0;t<4;++t)
                af[t]  = *(const bf16x8*)(&As[(mo + t*16 + l15)*64 + kc*32 + quad*8]);
            #pragma unroll
            for (int t=0;t<NT;++t)
                bfr[t] = *(const bf16x8*)(&Bs[(no + t*16 + l15)*64 + kc*32 + quad*8]);
            #pragma unroll
            for (int mt=0;mt<4;++mt)
              #pragma unroll
              for (int nt=0;nt<NT;++nt)
                acc[mt][nt] = __builtin_amdgcn_mfma_f32_16x16x32_bf16(af[mt], bfr[nt], acc[mt][nt], 0,0,0);
        }
        __syncthreads();
    }
    #pragma unroll
    for (int mt=0;mt<4;++mt){
      #pragma unroll
      for (int nt=0;nt<NT;++nt){
        int gn = n0 + no + nt*16 + l15;
        float bval = bias[gn];
        #pragma unroll
        for (int r=0;r<4;++r){
            int gm = m0 + mo + mt*16 + quad*4 + r;
            size_t off = (size_t)gm*Ndim + gn;
            float v = acc[mt][nt][r] + bval;
            if constexpr (HAS_RES) v += res[off];
            if constexpr (ACT == 1) v = gelu_f(v);
            if constexpr (OUT_BF16) ((unsigned short*)outp)[off] = f2b(v);
            else                    ((float*)outp)[off] = v;
        }
      }
    }
}

// ---------------- V pre-transpose: qkv v-slice -> vT[bh][d=64][SEQ] -------
__global__ __launch_bounds__(256) void transpose_v(
    const unsigned short* __restrict__ qkv, unsigned short* __restrict__ vT)
{
    __shared__ unsigned int t[64*33];   // [k-row][d-pair], pad 33 -> conflict-free
    int bh = blockIdx.y;
    int t0 = blockIdx.x*64;
    int tid = threadIdx.x;
    const size_t base = (size_t)(bh>>4)*SEQ*QKVLD + (size_t)(bh&15)*64 + 2*DMODEL;
    #pragma unroll
    for (int i=0;i<2;++i){
        int idx = tid + i*256;          // 0..511
        int r = idx>>3, cc = idx&7;     // k-row 0..63, d-chunk
        uint4 vv = *(const uint4*)(qkv + base + (size_t)(t0+r)*QKVLD + cc*8);
        t[r*33 + cc*4 + 0] = vv.x;
        t[r*33 + cc*4 + 1] = vv.y;
        t[r*33 + cc*4 + 2] = vv.z;
        t[r*33 + cc*4 + 3] = vv.w;
    }
    __syncthreads();
    unsigned short* outb = vT + (size_t)bh*64*SEQ + t0;
    #pragma unroll
    for (int i=0;i<2;++i){
        int idx = tid + i*256;
        int d = idx>>3, cc = idx&7;     // d-row 0..63, k-chunk
        int sh = (d&1)*16, dp = d>>1;
        unsigned int o4[4];
        #pragma unroll
        for (int j2=0;j2<4;++j2){
            unsigned int ua = t[(cc*8 + 2*j2    )*33 + dp];
            unsigned int ub = t[(cc*8 + 2*j2 + 1)*33 + dp];
            unsigned int ha = (ua >> sh) & 0xffff;
            unsigned int hb = (ub >> sh) & 0xffff;
            o4[j2] = ha | (hb << 16);
        }
        *(uint4*)(outb + (size_t)d*SEQ + cc*8) = *(uint4*)o4;
    }
}

// ---------------- flash attention, causal, 16 heads of 64 ------------------
// q/k from fused qkv (row stride QKVLD); v pre-transposed in vT.
// q-tile 128 (wave owns 32 rows = 2 sequential 16-row subs), KV tile 128,
// staged via global_load_lds into UNPADDED LDS with both-sides XOR swizzle.
__device__ __forceinline__ void stage_kv(
    const unsigned short* __restrict__ k, const unsigned short* __restrict__ vTb,
    int t0, unsigned short* Ks, unsigned short* Vt, int wv, int lane)
{
    #pragma unroll
    for (int p=0;p<4;++p){
        int c0 = p*256 + wv*64;         // wave-uniform chunk base
        int c  = c0 + lane;             // this lane's chunk
        int kr = c>>3, kc = (c&7)*8;    // K: row 0..127, col-chunk
        int vr = c>>4, vc = (c&15)*8;   // V: row 0..63,  col-chunk
        gload16(k   + (size_t)(t0+kr)*QKVLD + (kc ^ ((kr&7)<<3)), Ks + c0*8);
        gload16(vTb + (size_t)vr*SEQ + t0 +   (vc ^ ((vr&7)<<3)), Vt + c0*8);
    }
}

__global__ __launch_bounds__(256,2) void attn_flash(
    const unsigned short* __restrict__ qkv, const unsigned short* __restrict__ vT,
    unsigned short* __restrict__ attn)
{
    __shared__ unsigned short Ks[128*64];   // [k][d], unpadded, col-swizzled
    __shared__ unsigned short Vt[64*128];   // [d][k], unpadded, col-swizzled
    __shared__ unsigned short Ps[64*136];   // [q-sub][k], pad 8, per-wave 16 rows
    int bh = blockIdx.y;
    int qt = (int)gridDim.x - 1 - (int)blockIdx.x;   // heavy blocks first
    int q0 = qt*128;
    int tid = threadIdx.x, wv = tid>>6, lane = tid&63;
    int l15 = lane&15, quad = lane>>4;
    int xsw = (l15&7)<<3;                   // read-side XOR (row&7 == l15&7)
    const size_t basei = (size_t)(bh>>4)*SEQ*QKVLD + (size_t)(bh&15)*64;
    const unsigned short* q = qkv + basei;
    const unsigned short* k = qkv + basei + DMODEL;
    const unsigned short* vTb = vT + (size_t)bh*64*SEQ;
    const size_t baseo = (size_t)(bh>>4)*SEQ*DMODEL + (size_t)(bh&15)*64;

    int nkt = qt + 1;   // number of 128-wide kv tiles (causal)

    stage_kv(k, vTb, 0, Ks, Vt, wv, lane);

    // Q fragments directly from global (no LDS round-trip); 2 subs of 16 rows
    bf16x8 aq[2][2];
    #pragma unroll
    for (int s=0;s<2;++s){
        int qr = q0 + wv*32 + s*16 + l15;
        aq[s][0] = *(const bf16x8*)(q + (size_t)qr*QKVLD + quad*8);
        aq[s][1] = *(const bf16x8*)(q + (size_t)qr*QKVLD + 32 + quad*8);
    }

    float m_i[2][4], l_i[2][4];
    f32x4 zz = {0.f,0.f,0.f,0.f};
    f32x4 o[2][4];
    #pragma unroll
    for (int s=0;s<2;++s)
      #pragma unroll
      for (int r=0;r<4;++r){ m_i[s][r] = -__builtin_inff(); l_i[s][r] = 0.f; }
    #pragma unroll
    for (int s=0;s<2;++s)
      #pragma unroll
      for (int d=0;d<4;++d) o[s][d] = zz;

    const float SCL = 0.1803368801111137f;   // 0.125 * log2(e): exp2-domain softmax

    __syncthreads();   // drains gload_lds vmcnt; tile 0 staged

    for (int kt = 0; kt < nkt; ++kt){
        int t0 = kt*128;
        bool diagt = (kt == qt);

        #pragma unroll
        for (int sub=0; sub<2; ++sub){
            // QK^T: 8 sub-tiles of 16 k-cols each
            f32x4 sc[8];
            #pragma unroll
            for (int st=0;st<8;++st){
                bf16x8 b0 = *(const bf16x8*)(&Ks[(st*16+l15)*64 + ((     quad*8) ^ xsw)]);
                bf16x8 b1 = *(const bf16x8*)(&Ks[(st*16+l15)*64 + ((32 + quad*8) ^ xsw)]);
                sc[st] = __builtin_amdgcn_mfma_f32_16x16x32_bf16(aq[sub][0], b0, zz, 0,0,0);
                sc[st] = __builtin_amdgcn_mfma_f32_16x16x32_bf16(aq[sub][1], b1, sc[st], 0,0,0);
            }
            int qrb = q0 + wv*32 + sub*16 + quad*4;
            float mrow[4];
            #pragma unroll
            for (int r=0;r<4;++r) mrow[r] = -__builtin_inff();
            #pragma unroll
            for (int st=0;st<8;++st)
              #pragma unroll
              for (int r=0;r<4;++r){
                float svv = sc[st][r]*SCL;
                if (diagt && (t0 + st*16 + l15 > qrb + r))
                    svv = -__builtin_inff();
                sc[st][r] = svv;
                mrow[r] = fmaxf(mrow[r], svv);
              }
            #pragma unroll
            for (int d=1; d<16; d<<=1)
              #pragma unroll
              for (int r=0;r<4;++r) mrow[r] = fmaxf(mrow[r], __shfl_xor(mrow[r], d));
            float alpha[4], rsum[4];
            #pragma unroll
            for (int r=0;r<4;++r){
                float mn = fmaxf(m_i[sub][r], mrow[r]);
                alpha[r] = exp_2s(m_i[sub][r] - mn);
                m_i[sub][r] = mn;
            }
            #pragma unroll
            for (int st=0;st<8;++st)
              #pragma unroll
              for (int r=0;r<4;++r) sc[st][r] = exp_2s(sc[st][r] - m_i[sub][r]);
            #pragma unroll
            for (int r=0;r<4;++r){
                rsum[r] = ((sc[0][r]+sc[1][r])+(sc[2][r]+sc[3][r]))
                        + ((sc[4][r]+sc[5][r])+(sc[6][r]+sc[7][r]));
            }
            #pragma unroll
            for (int d=1; d<16; d<<=1)
              #pragma unroll
              for (int r=0;r<4;++r) rsum[r] += __shfl_xor(rsum[r], d);
            #pragma unroll
            for (int r=0;r<4;++r) l_i[sub][r] = l_i[sub][r]*alpha[r] + rsum[r];
            // P -> LDS (own wave's 16 rows; per-wave DS ordering, no barrier)
            #pragma unroll
            for (int st=0;st<8;++st)
              #pragma unroll
              for (int r=0;r<4;++r)
                Ps[(wv*16 + quad*4 + r)*136 + st*16 + l15] = f2b(sc[st][r]);
            #pragma unroll
            for (int d=0;d<4;++d)
              #pragma unroll
              for (int r=0;r<4;++r) o[sub][d][r] = o[sub][d][r]*alpha[r];

            // PV: O[q][d] += P[q][0..127] @ V^T[d][0..127]
            bf16x8 ap[4];
            #pragma unroll
            for (int kch=0;kch<4;++kch)
                ap[kch] = *(const bf16x8*)(&Ps[(wv*16 + l15)*136 + kch*32 + quad*8]);
            #pragma unroll
            for (int dtile=0;dtile<4;++dtile){
                #pragma unroll
                for (int kch=0;kch<4;++kch){
                    bf16x8 bv_ = *(const bf16x8*)(&Vt[(dtile*16+l15)*128 + ((kch*32 + quad*8) ^ xsw)]);
                    o[sub][dtile] = __builtin_amdgcn_mfma_f32_16x16x32_bf16(ap[kch], bv_, o[sub][dtile], 0,0,0);
                }
            }
        }

        if (kt + 1 < nkt){
            __syncthreads();                 // all waves done reading tile kt
            stage_kv(k, vTb, t0 + 128, Ks, Vt, wv, lane);
            __syncthreads();                 // drains vmcnt; tile kt+1 staged
        }
    }
    #pragma unroll
    for (int sub=0; sub<2; ++sub)
      #pragma unroll
      for (int r=0;r<4;++r){
        float inv = 1.f/l_i[sub][r];
        int gm = q0 + wv*32 + sub*16 + quad*4 + r;
        #pragma unroll
        for (int dtile=0;dtile<4;++dtile)
            attn[baseo + (size_t)gm*DMODEL + dtile*16 + l15] = f2b(o[sub][dtile][r]*inv);
      }
}

// ---------------- depthwise causal conv(4) + bias + silu -------------------
__global__ __launch_bounds__(256) void conv_silu(
    const unsigned short* __restrict__ xr, const float* __restrict__ cw,
    const float* __restrict__ cb, unsigned short* __restrict__ xm2)
{
    int idx = blockIdx.x*256 + threadIdx.x;
    int r  = idx >> 10;
    int c2 = (idx & 1023)*2;
    int s  = r & (SEQ-1);
    float4 w0 = *(const float4*)(cw + c2*4);
    float4 w1 = *(const float4*)(cw + (c2+1)*4);
    float w0a[4] = {w0.x,w0.y,w0.z,w0.w};
    float w1a[4] = {w1.x,w1.y,w1.z,w1.w};
    float a0 = cb[c2], a1 = cb[c2+1];
    const unsigned short* xrow = xr + (size_t)r*DFF + c2;
    #pragma unroll
    for (int j=0;j<4;++j){
        int sp = s - 3 + j;
        if (sp >= 0){
            int off = (j-3)*DFF;
            unsigned int u = *(const unsigned int*)(xrow + off);
            a0 += w0a[j]*b2f(u & 0xffff);
            a1 += w1a[j]*b2f(u >> 16);
        }
    }
    float s0 = a0 * __builtin_amdgcn_rcpf(1.f + __expf(-a0));
    float s1 = a1 * __builtin_amdgcn_rcpf(1.f + __expf(-a1));
    unsigned int op = (unsigned int)f2b(s0) | ((unsigned int)f2b(s1) << 16);
    *(unsigned int*)(xm2 + (size_t)r*DINNER + c2) = op;
}

// ---------------- xdbl = xm2 @ xp_w + xp_b, written as {b,c+1} pairs -------
__global__ __launch_bounds__(256) void xp_gemm(
    const unsigned short* __restrict__ xm2, const float* __restrict__ w,
    const float* __restrict__ bias, float* __restrict__ xdbl)
{
    int tid = threadIdx.x;
    int lr = tid >> 5, n = tid & 31;
    int row = blockIdx.x*8 + lr;
    const unsigned short* ar = xm2 + (size_t)row*DINNER;
    float acc = bias[n];
    #pragma unroll 4
    for (int k2 = 0; k2 < DINNER; k2 += 2){
        unsigned int u = *(const unsigned int*)(ar + k2);
        acc += b2f(u & 0xffff)*w[k2*32 + n] + b2f(u >> 16)*w[(k2+1)*32 + n];
    }
    if (n >= 16) acc += 1.f;                // c-columns carry +1 for scan's u
    int nc = (n < 16) ? 2*n : 2*(n-16)+1;   // interleave: {b_i,c_i} adjacent
    xdbl[(size_t)row*32 + nc] = acc;
}

// ---------------- sequential scan: packed-f16 dot2 + register bc banks -----
// h_{t+1}[i] = tanh(sum_j exp(dtp*A[i][j]) h_t[j]) + b_t[i]*h_t[i] + c_t[i]
// Weights pre-scaled by 2*log2e: x2 = sum (W') h, e^(2s) = exp2(x2),
// tanh = 1 - 2/(e^(2s)+1); h' = fma(-2, rcp(e2+1), (b*h + (c+1))).
// Chained 2x4 fdot2 (R10 form): accumulate is free inside dot2; minimal
// instruction count wins in this 1-wave/SIMD kernel (R11 tree regressed 47%).
__device__ __forceinline__ float scan_step_dot(float h, const f16x2 (&Wp)[8],
                                               float bv, float cv)
{
    float rr = dppf<0x121>(h);
    f16x2 p0 = __builtin_amdgcn_cvt_pkrtz(h, rr);
    f16x2 p1 = dpp_h2<0x122>(p0);
    f16x2 p2 = dpp_h2<0x124>(p0);
    f16x2 p3 = dpp_h2<0x126>(p0);
    f16x2 p4 = dpp_h2<0x128>(p0);
    f16x2 p5 = dpp_h2<0x12a>(p0);
    f16x2 p6 = dpp_h2<0x12c>(p0);
    f16x2 p7 = dpp_h2<0x12e>(p0);
    float a0 = hdot2(Wp[0], p0, 0.f);
    a0 = hdot2(Wp[1], p1, a0);
    a0 = hdot2(Wp[2], p2, a0);
    a0 = hdot2(Wp[3], p3, a0);
    float a1 = hdot2(Wp[4], p4, 0.f);
    a1 = hdot2(Wp[5], p5, a1);
    a1 = hdot2(Wp[6], p6, a1);
    a1 = hdot2(Wp[7], p7, a1);
    float u  = fmaf(bv, h, cv);                // cv already includes +1
    float e2 = exp_2s(a0 + a1);
    float r  = __builtin_amdgcn_rcpf(e2 + 1.f);
    return fmaf(-2.f, r, u);
}

__device__ __forceinline__ void load_bank(float2 (&bk)[16], const float* src){
    #pragma unroll
    for (int j=0;j<16;++j) bk[j] = *(const float2*)(src + (size_t)j*32);
}

__device__ __forceinline__ void compute16(const float2 (&bk)[16],
                                          const f16x2 (&Wf)[16][8],
                                          float& hn, float* hp, int lane)
{
    float h0s=0.f, h1s=0.f, h2s=0.f;
    #pragma unroll
    for (int j=0;j<16;++j){
        // global t = blk*16 + j -> phase t%16 == j (static weight index)
        hn = scan_step_dot(hn, Wf[j], bk[j].x, bk[j].y);
        if ((j&3)==0)      h0s = hn;
        else if ((j&3)==1) h1s = hn;
        else if ((j&3)==2) h2s = hn;
        else if (lane < 16){
            float4 o4 = {h0s, h1s, h2s, hn};
            *(float4*)(hp + j - 3) = o4;
        }
    }
}

__global__ __launch_bounds__(128,1) void scan_k(
    const float* __restrict__ xdbl, const float* __restrict__ dt,
    const float* __restrict__ A, float* __restrict__ hsT)
{
    int tid = threadIdx.x;
    int lane = tid & 63;
    int b = tid >> 6;
    int i = lane & 15;

    // probe: identical DPP fan applied to lane index -> actual source lanes.
    // pair j of the packed fan covers sources (sj[j], tj[j]).
    int c1 = dppi<0x121>(i);
    int sj[8], tj[8];
    sj[0] = i;               tj[0] = c1;
    sj[1] = dppi<0x122>(i);  tj[1] = dppi<0x122>(c1);
    sj[2] = dppi<0x124>(i);  tj[2] = dppi<0x124>(c1);
    sj[3] = dppi<0x126>(i);  tj[3] = dppi<0x126>(c1);
    sj[4] = dppi<0x128>(i);  tj[4] = dppi<0x128>(c1);
    sj[5] = dppi<0x12a>(i);  tj[5] = dppi<0x12a>(c1);
    sj[6] = dppi<0x12c>(i);  tj[6] = dppi<0x12c>(c1);
    sj[7] = dppi<0x12e>(i);  tj[7] = dppi<0x12e>(c1);

    // packed-f16 weight table: 16 phases x 8 pairs = 128 VGPRs
    f16x2 Wf[16][8];
    #pragma unroll
    for (int p=0;p<16;++p){
        float dtp = __expf(dt[p]);
        #pragma unroll
        for (int jj=0;jj<8;++jj){
            float w0 = W_SCALE*__expf(dtp * A[i*16 + sj[jj]]);
            float w1 = W_SCALE*__expf(dtp * A[i*16 + tj[jj]]);
            Wf[p][jj] = __builtin_amdgcn_cvt_pkrtz(w0, w1);
        }
    }

    // b/c stream: global -> 2x16 float2 register banks, 16-step prefetch lead
    const float* src = xdbl + (size_t)(b*SEQ)*32 + 2*i;
    float* hp = hsT + (size_t)(b*16 + i)*SEQ;
    float2 bA[16], bB[16];
    load_bank(bA, src);
    float hn = 0.f;
    for (int bp = 0; bp < 64; ++bp){
        int t0 = bp*32;
        load_bank(bB, src + (size_t)(t0+16)*32);
        compute16(bA, Wf, hn, hp + t0, lane);
        int t2 = (bp < 63) ? (t0 + 32) : 0;      // last iter: dummy reload of blk 0
        load_bank(bA, src + (size_t)t2*32);
        compute16(bB, Wf, hn, hp + t0 + 16, lane);
    }
}

// ---------------- y = repeat(hsT,128) + res (bf16) -------------------------
__global__ __launch_bounds__(256) void y_assemble(
    const float* __restrict__ hsT, const unsigned short* __restrict__ xr,
    unsigned short* __restrict__ y)
{
    int idx = blockIdx.x*256 + threadIdx.x;
    int r = idx >> 10;
    int c2 = (idx & 1023)*2;
    int bb = r >> 11, s = r & (SEQ-1);
    unsigned int u = *(const unsigned int*)(xr + (size_t)r*DFF + DINNER + c2);
    float h0 = hsT[(size_t)(bb*16 + (c2 >> 7))*SEQ + s];
    float y0 = h0 + b2f(u & 0xffff);
    float y1 = h0 + b2f(u >> 16);
    *(unsigned int*)(y + (size_t)r*DINNER + c2) =
        (unsigned int)f2b(y0) | ((unsigned int)f2b(y1) << 16);
}

// ---------------------------------------------------------------------------
extern "C" void kernel_launch(void* const* d_in, const int* in_sizes, int n_in,
                              void* d_out, int out_size, void* d_ws, size_t ws_size,
                              hipStream_t stream)
{
    (void)in_sizes; (void)n_in; (void)out_size; (void)ws_size;
    const float* x     = (const float*)d_in[0];
    const float* ln1_g = (const float*)d_in[1];
    const float* ln1_b = (const float*)d_in[2];
    const float* Wq    = (const float*)d_in[3];
    const float* bq    = (const float*)d_in[4];
    const float* Wk    = (const float*)d_in[5];
    const float* bk    = (const float*)d_in[6];
    const float* Wv    = (const float*)d_in[7];
    const float* bv    = (const float*)d_in[8];
    const float* Wo    = (const float*)d_in[9];
    const float* bo    = (const float*)d_in[10];
    const float* ln2_g = (const float*)d_in[11];
    const float* ln2_b = (const float*)d_in[12];
    const float* in_w  = (const float*)d_in[13];
    const float* in_b  = (const float*)d_in[14];
    const float* conv_w= (const float*)d_in[15];
    const float* conv_b= (const float*)d_in[16];
    const float* xp_w  = (const float*)d_in[17];
    const float* xp_b  = (const float*)d_in[18];
    const float* dt    = (const float*)d_in[19];
    const float* A     = (const float*)d_in[20];
    const float* out_w = (const float*)d_in[22];
    const float* out_b = (const float*)d_in[23];
    const float* ln3_g = (const float*)d_in[24];
    const float* ln3_b = (const float*)d_in[25];
    const float* fc1_w = (const float*)d_in[26];
    const float* fc1_b = (const float*)d_in[27];
    const float* fc2_w = (const float*)d_in[28];
    const float* fc2_b = (const float*)d_in[29];

    char* ws = (char*)d_ws;
    const size_t MB = 1ull << 20;
    unsigned short* qkvT = (unsigned short*)(ws + 0*MB);   // WqT|WkT|WvT, 6MB
    unsigned short* WoT  = (unsigned short*)(ws + 6*MB);
    unsigned short* inT  = (unsigned short*)(ws + 8*MB);
    unsigned short* outT = (unsigned short*)(ws + 16*MB);
    unsigned short* f1T  = (unsigned short*)(ws + 20*MB);
    unsigned short* f2T  = (unsigned short*)(ws + 28*MB);
    unsigned short* hbf  = (unsigned short*)(ws + 36*MB);  // also vT window
    float*          x2   = (float*)(ws + 44*MB);
    float*          x3   = (float*)(ws + 60*MB);
    unsigned short* qkv  = (unsigned short*)(ws + 76*MB);  // 24MB fused QKV
    unsigned short* attnb= (unsigned short*)(ws + 100*MB);
    unsigned short* xr   = (unsigned short*)(ws + 76*MB);  // reuse after attn
    unsigned short* ffn  = (unsigned short*)(ws + 76*MB);  // reuse after y
    unsigned short* xm2  = (unsigned short*)(ws + 108*MB);
    unsigned short* yb   = (unsigned short*)(ws + 108*MB); // reuse after xp
    float*          xdbl = (float*)(ws + 124*MB);
    float*          hsb  = (float*)(ws + 124*MB + 512*1024);
    float*          bqkv = (float*)(ws + 125*MB);

    dim3 blk(256);
    transpose_cast<<<dim3(16,16), blk, 0, stream>>>(Wq, qkvT,              1024, 1024);
    transpose_cast<<<dim3(16,16), blk, 0, stream>>>(Wk, qkvT + 1024*1024,  1024, 1024);
    transpose_cast<<<dim3(16,16), blk, 0, stream>>>(Wv, qkvT + 2*1024*1024,1024, 1024);
    transpose_cast<<<dim3(16,16), blk, 0, stream>>>(Wo, WoT, 1024, 1024);
    transpose_cast<<<dim3(64,16), blk, 0, stream>>>(in_w, inT, 1024, 4096);
    transpose_cast<<<dim3(16,32), blk, 0, stream>>>(out_w, outT, 2048, 1024);
    transpose_cast<<<dim3(64,16), blk, 0, stream>>>(fc1_w, f1T, 1024, 4096);
    transpose_cast<<<dim3(16,64), blk, 0, stream>>>(fc2_w, f2T, 4096, 1024);
    concat_bias<<<12, blk, 0, stream>>>(bq, bk, bv, bqkv);

    layernorm_bf16<<<MROWS, blk, 0, stream>>>(x, ln1_g, ln1_b, hbf);
    gemm_bt<128,1,0,0><<<dim3(24,32), blk, 0, stream>>>(hbf, qkvT, bqkv, nullptr, qkv, QKVLD, 1024);
    transpose_v<<<dim3(32,32), blk, 0, stream>>>(qkv, hbf);   // vT in hbf window
    attn_flash<<<dim3(16,32), blk, 0, stream>>>(qkv, hbf, attnb);
    gemm_bt<64,0,1,0><<<dim3(16,32), blk, 0, stream>>>(attnb, WoT, bo, x, x2, 1024, 1024);
    layernorm_bf16<<<MROWS, blk, 0, stream>>>(x2, ln2_g, ln2_b, hbf);
    gemm_bt<128,1,0,0><<<dim3(32,32), blk, 0, stream>>>(hbf, inT, in_b, nullptr, xr, 4096, 1024);
    conv_silu<<<16384, blk, 0, stream>>>(xr, conv_w, conv_b, xm2);
    xp_gemm<<<512, blk, 0, stream>>>(xm2, xp_w, xp_b, xdbl);
    scan_k<<<1, dim3(128), 0, stream>>>(xdbl, dt, A, hsb);
    y_assemble<<<16384, blk, 0, stream>>>(hsb, xr, yb);
    gemm_bt<64,0,1,0><<<dim3(16,32), blk, 0, stream>>>(yb, outT, out_b, x2, x3, 1024, 2048);
    layernorm_bf16<<<MROWS, blk, 0, stream>>>(x3, ln3_g, ln3_b, hbf);
    gemm_bt<128,1,0,1><<<dim3(32,32), blk, 0, stream>>>(hbf, f1T, fc1_b, nullptr, ffn, 4096, 1024);
    gemm_bt<64,0,1,0><<<dim3(16,32), blk, 0, stream>>>(ffn, f2T, fc2_b, x3, (float*)d_out, 1024, 4096);
}

// Round 7
// 858.850 us; speedup vs baseline: 1.0385x; 1.0009x over previous
//
#include <hip/hip_runtime.h>
#include <hip/hip_bf16.h>

// ---------------------------------------------------------------------------
// R13 changes vs R12:
//  * attn_flash: double-buffered K/V LDS + counted-vmcnt pipeline (T3/T4).
//    Prefetch tile kt+1 via global_load_lds at top of iter kt; raw s_barrier
//    + inline `s_waitcnt vmcnt(8)` (8 prefetch loads stay in flight across
//    the barrier; the 8 oldest = tile kt's loads complete). Last iter waits
//    vmcnt(0) (no prefetch outstanding). sched_barrier(0) after the wait
//    pins LDS reads (rule #18). Ps un-padded + XOR-swizzled like K/V ->
//    LDS exactly 80KB -> still 2 blocks/CU.
//  * scan_k / gemm_bt / everything else unchanged from R12 (859.7us).
// ---------------------------------------------------------------------------

#define SEQ     2048
#define BATCH   2
#define MROWS   4096      // BATCH*SEQ
#define DMODEL  1024
#define DINNER  2048
#define DFF     4096
#define QKVLD   3072

typedef __attribute__((ext_vector_type(8))) short bf16x8;
typedef __attribute__((ext_vector_type(4))) float f32x4;
typedef __attribute__((ext_vector_type(2))) __fp16 f16x2;

__device__ __forceinline__ unsigned short f2b(float x){
    __hip_bfloat16 h = __float2bfloat16(x);
    return *reinterpret_cast<unsigned short*>(&h);
}
__device__ __forceinline__ float b2f(unsigned short u){
    __hip_bfloat16 h;
    *reinterpret_cast<unsigned short*>(&h) = u;
    return __bfloat162float(h);
}
__device__ __forceinline__ float gelu_f(float v){
    float u = 0.7978845608f*(v + 0.044715f*v*v*v);
    float e = __expf(2.f*u);
    float th = 1.f - 2.f*__builtin_amdgcn_rcpf(e + 1.f);
    return 0.5f*v*(1.f + th);
}
__device__ __forceinline__ void gload16(const unsigned short* g, unsigned short* l){
    __builtin_amdgcn_global_load_lds(
        (const __attribute__((address_space(1))) void*)g,
        (__attribute__((address_space(3))) void*)l, 16, 0, 0);
}
template<int CTRL>
__device__ __forceinline__ float dppf(float x){
    int r = __builtin_amdgcn_mov_dpp(__builtin_bit_cast(int, x), CTRL, 0xf, 0xf, false);
    return __builtin_bit_cast(float, r);
}
template<int CTRL>
__device__ __forceinline__ int dppi(int x){
    return __builtin_amdgcn_mov_dpp(x, CTRL, 0xf, 0xf, false);
}
template<int CTRL>
__device__ __forceinline__ f16x2 dpp_h2(f16x2 x){
    int r = __builtin_amdgcn_mov_dpp(__builtin_bit_cast(int, x), CTRL, 0xf, 0xf, false);
    return __builtin_bit_cast(f16x2, r);
}

#if __has_builtin(__builtin_amdgcn_exp2f)
#define W_SCALE 2.8853900817779268f   /* 2*log2(e): x2 = 2*log2e*s, e^(2s)=2^x2 */
__device__ __forceinline__ float exp_2s(float x){ return __builtin_amdgcn_exp2f(x); }
#else
#define W_SCALE 2.0f
__device__ __forceinline__ float exp_2s(float x){ return __expf(x); }
#endif

__device__ __forceinline__ float hdot2(f16x2 a, f16x2 b, float c){
#if __has_builtin(__builtin_amdgcn_fdot2)
    return __builtin_amdgcn_fdot2(a, b, c, false);
#else
    return c + (float)a[0]*(float)b[0] + (float)a[1]*(float)b[1];
#endif
}

// ---------------- transpose + cast: W (KxN f32) -> Wt (NxK bf16) ----------
__global__ __launch_bounds__(256) void transpose_cast(
    const float* __restrict__ W, unsigned short* __restrict__ Wt, int K, int N)
{
    __shared__ float t[64*65];
    int n0 = blockIdx.x*64, k0 = blockIdx.y*64;
    int c = threadIdx.x & 63, r0 = threadIdx.x >> 6;
    #pragma unroll
    for (int rr = 0; rr < 64; rr += 4)
        t[(rr+r0)*65 + c] = W[(size_t)(k0+rr+r0)*N + n0 + c];
    __syncthreads();
    #pragma unroll
    for (int rr = 0; rr < 64; rr += 4)
        Wt[(size_t)(n0+rr+r0)*K + k0 + c] = f2b(t[c*65 + rr + r0]);
}

// ---------------- concat 3 bias vectors --------------------------------
__global__ __launch_bounds__(256) void concat_bias(
    const float* __restrict__ b0, const float* __restrict__ b1,
    const float* __restrict__ b2, float* __restrict__ o)
{
    int t = blockIdx.x*256 + threadIdx.x;
    float v = (t < 1024) ? b0[t] : (t < 2048 ? b1[t-1024] : b2[t-2048]);
    o[t] = v;
}

// ---------------- layernorm row=1024, f32 in -> bf16 out ------------------
__global__ __launch_bounds__(256) void layernorm_bf16(
    const float* __restrict__ x, const float* __restrict__ g,
    const float* __restrict__ b, unsigned short* __restrict__ out)
{
    int row = blockIdx.x;
    const float4* xr = (const float4*)(x + (size_t)row*DMODEL);
    int tid = threadIdx.x;
    float4 xv = xr[tid];
    float s  = xv.x + xv.y + xv.z + xv.w;
    float ss = xv.x*xv.x + xv.y*xv.y + xv.z*xv.z + xv.w*xv.w;
    #pragma unroll
    for (int d = 32; d > 0; d >>= 1){ s += __shfl_xor(s,d); ss += __shfl_xor(ss,d); }
    __shared__ float sm[8];
    int wv = tid>>6, ln = tid&63;
    if (ln == 0){ sm[wv] = s; sm[4+wv] = ss; }
    __syncthreads();
    s  = sm[0]+sm[1]+sm[2]+sm[3];
    ss = sm[4]+sm[5]+sm[6]+sm[7];
    float mean = s*(1.f/DMODEL);
    float var  = ss*(1.f/DMODEL) - mean*mean;
    float rstd = rsqrtf(var + 1e-5f);
    float4 gv = ((const float4*)g)[tid];
    float4 bv = ((const float4*)b)[tid];
    ushort4 o;
    o.x = f2b((xv.x-mean)*rstd*gv.x + bv.x);
    o.y = f2b((xv.y-mean)*rstd*gv.y + bv.y);
    o.z = f2b((xv.z-mean)*rstd*gv.z + bv.z);
    o.w = f2b((xv.w-mean)*rstd*gv.w + bv.w);
    ((ushort4*)(out + (size_t)row*DMODEL))[tid] = o;
}

// ---------------- GEMM: C[M,N] = act(A[M,K] @ Bt[N,K]^T + bias) (+res) ----
// 128xBN tile, 4 waves (2x2), wave does 64x(BN/2). BK=64. global_load_lds.
template<int BN, int OUT_BF16, int HAS_RES, int ACT>
__global__ __launch_bounds__(256,3) void gemm_bt(
    const unsigned short* __restrict__ A, const unsigned short* __restrict__ Bt,
    const float* __restrict__ bias, const float* __restrict__ res,
    void* __restrict__ outp, int Ndim, int Kdim)
{
    constexpr int NT = BN/32;               // n-tiles per wave
    constexpr int BROWS = BN/32;            // B staging iters per wave (8 rows each)
    __shared__ unsigned short As[128*64];   // unpadded: required by global_load_lds
    __shared__ unsigned short Bs[BN*64];
    int tid = threadIdx.x;
    int lane = tid & 63, wv = tid >> 6;
    int l15 = lane & 15, quad = lane >> 4;
    int m0 = blockIdx.y*128, n0 = blockIdx.x*BN;
    int mo = (wv>>1)*64, no = (wv&1)*(BN/2);
    int rsub = (lane >> 3);          // 0..7
    int cc8  = (lane & 7)*8;         // element col within 64
    f32x4 zz = {0.f,0.f,0.f,0.f};
    f32x4 acc[4][NT];
    #pragma unroll
    for (int i=0;i<4;++i)
      #pragma unroll
      for (int j=0;j<NT;++j) acc[i][j] = zz;

    for (int k0 = 0; k0 < Kdim; k0 += 64){
        const unsigned short* Ab = A  + (size_t)(m0 + wv*32 + rsub)*Kdim + k0 + cc8;
        const unsigned short* Bb = Bt + (size_t)(n0 + wv*(BN/4) + rsub)*Kdim + k0 + cc8;
        #pragma unroll
        for (int i=0;i<4;++i)
            gload16(Ab + (size_t)(i*8)*Kdim, &As[(wv*32 + i*8)*64]);
        #pragma unroll
        for (int i=0;i<BROWS;++i)
            gload16(Bb + (size_t)(i*8)*Kdim, &Bs[(wv*(BN/4) + i*8)*64]);
        __syncthreads();
        #pragma unroll
        for (int kc=0;kc<2;++kc){
            bf16x8 af[4], bfr[NT];
            #pragma unroll
            for (int t=0;t<4;++t)
                af[t]  = *(const bf16x8*)(&As[(mo + t*16 + l15)*64 + kc*32 + quad*8]);
            #pragma unroll
            for (int t=0;t<NT;++t)
                bfr[t] = *(const bf16x8*)(&Bs[(no + t*16 + l15)*64 + kc*32 + quad*8]);
            #pragma unroll
            for (int mt=0;mt<4;++mt)
              #pragma unroll
              for (int nt=0;nt<NT;++nt)
                acc[mt][nt] = __builtin_amdgcn_mfma_f32_16x16x32_bf16(af[mt], bfr[nt], acc[mt][nt], 0,0,0);
        }
        __syncthreads();
    }
    #pragma unroll
    for (int mt=0;mt<4;++mt){
      #pragma unroll
      for (int nt=0;nt<NT;++nt){
        int gn = n0 + no + nt*16 + l15;
        float bval = bias[gn];
        #pragma unroll
        for (int r=0;r<4;++r){
            int gm = m0 + mo + mt*16 + quad*4 + r;
            size_t off = (size_t)gm*Ndim + gn;
            float v = acc[mt][nt][r] + bval;
            if constexpr (HAS_RES) v += res[off];
            if constexpr (ACT == 1) v = gelu_f(v);
            if constexpr (OUT_BF16) ((unsigned short*)outp)[off] = f2b(v);
            else                    ((float*)outp)[off] = v;
        }
      }
    }
}

// ---------------- V pre-transpose: qkv v-slice -> vT[bh][d=64][SEQ] -------
__global__ __launch_bounds__(256) void transpose_v(
    const unsigned short* __restrict__ qkv, unsigned short* __restrict__ vT)
{
    __shared__ unsigned int t[64*33];   // [k-row][d-pair], pad 33 -> conflict-free
    int bh = blockIdx.y;
    int t0 = blockIdx.x*64;
    int tid = threadIdx.x;
    const size_t base = (size_t)(bh>>4)*SEQ*QKVLD + (size_t)(bh&15)*64 + 2*DMODEL;
    #pragma unroll
    for (int i=0;i<2;++i){
        int idx = tid + i*256;          // 0..511
        int r = idx>>3, cc = idx&7;     // k-row 0..63, d-chunk
        uint4 vv = *(const uint4*)(qkv + base + (size_t)(t0+r)*QKVLD + cc*8);
        t[r*33 + cc*4 + 0] = vv.x;
        t[r*33 + cc*4 + 1] = vv.y;
        t[r*33 + cc*4 + 2] = vv.z;
        t[r*33 + cc*4 + 3] = vv.w;
    }
    __syncthreads();
    unsigned short* outb = vT + (size_t)bh*64*SEQ + t0;
    #pragma unroll
    for (int i=0;i<2;++i){
        int idx = tid + i*256;
        int d = idx>>3, cc = idx&7;     // d-row 0..63, k-chunk
        int sh = (d&1)*16, dp = d>>1;
        unsigned int o4[4];
        #pragma unroll
        for (int j2=0;j2<4;++j2){
            unsigned int ua = t[(cc*8 + 2*j2    )*33 + dp];
            unsigned int ub = t[(cc*8 + 2*j2 + 1)*33 + dp];
            unsigned int ha = (ua >> sh) & 0xffff;
            unsigned int hb = (ub >> sh) & 0xffff;
            o4[j2] = ha | (hb << 16);
        }
        *(uint4*)(outb + (size_t)d*SEQ + cc*8) = *(uint4*)o4;
    }
}

// ---------------- flash attention, causal, 16 heads of 64 ------------------
// q/k from fused qkv (row stride QKVLD); v pre-transposed in vT.
// q-tile 128 (wave owns 32 rows = 2 sequential 16-row subs), KV tile 128,
// double-buffered global_load_lds staging with counted vmcnt across raw
// barriers; unpadded LDS, both-sides XOR swizzle everywhere.
__device__ __forceinline__ void stage_kv(
    const unsigned short* __restrict__ k, const unsigned short* __restrict__ vTb,
    int t0, unsigned short* Ks, unsigned short* Vt, int wv, int lane)
{
    #pragma unroll
    for (int p=0;p<4;++p){
        int c0 = p*256 + wv*64;         // wave-uniform chunk base
        int c  = c0 + lane;             // this lane's chunk
        int kr = c>>3, kc = (c&7)*8;    // K: row 0..127, col-chunk
        int vr = c>>4, vc = (c&15)*8;   // V: row 0..63,  col-chunk
        gload16(k   + (size_t)(t0+kr)*QKVLD + (kc ^ ((kr&7)<<3)), Ks + c0*8);
        gload16(vTb + (size_t)vr*SEQ + t0 +   (vc ^ ((vr&7)<<3)), Vt + c0*8);
    }
}

__global__ __launch_bounds__(256,2) void attn_flash(
    const unsigned short* __restrict__ qkv, const unsigned short* __restrict__ vT,
    unsigned short* __restrict__ attn)
{
    __shared__ unsigned short Ks[2][128*64];  // [buf][k][d], col-swizzled
    __shared__ unsigned short Vt[2][64*128];  // [buf][d][k], col-swizzled
    __shared__ unsigned short Ps[64*128];     // [q-sub][k], col-swizzled
    int bh = blockIdx.y;
    int qt = (int)gridDim.x - 1 - (int)blockIdx.x;   // heavy blocks first
    int q0 = qt*128;
    int tid = threadIdx.x, wv = tid>>6, lane = tid&63;
    int l15 = lane&15, quad = lane>>4;
    int xsw = (l15&7)<<3;                   // read-side XOR (row&7 == l15&7)
    const size_t basei = (size_t)(bh>>4)*SEQ*QKVLD + (size_t)(bh&15)*64;
    const unsigned short* q = qkv + basei;
    const unsigned short* k = qkv + basei + DMODEL;
    const unsigned short* vTb = vT + (size_t)bh*64*SEQ;
    const size_t baseo = (size_t)(bh>>4)*SEQ*DMODEL + (size_t)(bh&15)*64;

    int nkt = qt + 1;   // number of 128-wide kv tiles (causal)

    stage_kv(k, vTb, 0, Ks[0], Vt[0], wv, lane);

    // Q fragments directly from global (no LDS round-trip); 2 subs of 16 rows
    bf16x8 aq[2][2];
    #pragma unroll
    for (int s=0;s<2;++s){
        int qr = q0 + wv*32 + s*16 + l15;
        aq[s][0] = *(const bf16x8*)(q + (size_t)qr*QKVLD + quad*8);
        aq[s][1] = *(const bf16x8*)(q + (size_t)qr*QKVLD + 32 + quad*8);
    }

    float m_i[2][4], l_i[2][4];
    f32x4 zz = {0.f,0.f,0.f,0.f};
    f32x4 o[2][4];
    #pragma unroll
    for (int s=0;s<2;++s)
      #pragma unroll
      for (int r=0;r<4;++r){ m_i[s][r] = -__builtin_inff(); l_i[s][r] = 0.f; }
    #pragma unroll
    for (int s=0;s<2;++s)
      #pragma unroll
      for (int d=0;d<4;++d) o[s][d] = zz;

    const float SCL = 0.1803368801111137f;   // 0.125 * log2(e): exp2-domain softmax

    asm volatile("s_waitcnt vmcnt(0)" ::: "memory");   // tile 0 + Q landed
    __builtin_amdgcn_s_barrier();

    for (int kt = 0; kt < nkt; ++kt){
        int t0 = kt*128;
        bool diagt = (kt == qt);
        int cur = kt & 1;
        const unsigned short* Kc = Ks[cur];
        const unsigned short* Vc = Vt[cur];

        if (kt + 1 < nkt){
            stage_kv(k, vTb, t0 + 128, Ks[cur^1], Vt[cur^1], wv, lane);
            // 8 prefetch loads in flight; wait for the 8 older (tile kt) only
            asm volatile("s_waitcnt vmcnt(8)" ::: "memory");
        } else {
            asm volatile("s_waitcnt vmcnt(0)" ::: "memory");
        }
        __builtin_amdgcn_sched_barrier(0);
        __builtin_amdgcn_s_barrier();       // all waves: tile kt staged

        #pragma unroll
        for (int sub=0; sub<2; ++sub){
            // QK^T: 8 sub-tiles of 16 k-cols each
            f32x4 sc[8];
            #pragma unroll
            for (int st=0;st<8;++st){
                bf16x8 b0 = *(const bf16x8*)(&Kc[(st*16+l15)*64 + ((     quad*8) ^ xsw)]);
                bf16x8 b1 = *(const bf16x8*)(&Kc[(st*16+l15)*64 + ((32 + quad*8) ^ xsw)]);
                sc[st] = __builtin_amdgcn_mfma_f32_16x16x32_bf16(aq[sub][0], b0, zz, 0,0,0);
                sc[st] = __builtin_amdgcn_mfma_f32_16x16x32_bf16(aq[sub][1], b1, sc[st], 0,0,0);
            }
            int qrb = q0 + wv*32 + sub*16 + quad*4;
            float mrow[4];
            #pragma unroll
            for (int r=0;r<4;++r) mrow[r] = -__builtin_inff();
            #pragma unroll
            for (int st=0;st<8;++st)
              #pragma unroll
              for (int r=0;r<4;++r){
                float svv = sc[st][r]*SCL;
                if (diagt && (t0 + st*16 + l15 > qrb + r))
                    svv = -__builtin_inff();
                sc[st][r] = svv;
                mrow[r] = fmaxf(mrow[r], svv);
              }
            #pragma unroll
            for (int d=1; d<16; d<<=1)
              #pragma unroll
              for (int r=0;r<4;++r) mrow[r] = fmaxf(mrow[r], __shfl_xor(mrow[r], d));
            float alpha[4], rsum[4];
            #pragma unroll
            for (int r=0;r<4;++r){
                float mn = fmaxf(m_i[sub][r], mrow[r]);
                alpha[r] = exp_2s(m_i[sub][r] - mn);
                m_i[sub][r] = mn;
            }
            #pragma unroll
            for (int st=0;st<8;++st)
              #pragma unroll
              for (int r=0;r<4;++r) sc[st][r] = exp_2s(sc[st][r] - m_i[sub][r]);
            #pragma unroll
            for (int r=0;r<4;++r){
                rsum[r] = ((sc[0][r]+sc[1][r])+(sc[2][r]+sc[3][r]))
                        + ((sc[4][r]+sc[5][r])+(sc[6][r]+sc[7][r]));
            }
            #pragma unroll
            for (int d=1; d<16; d<<=1)
              #pragma unroll
              for (int r=0;r<4;++r) rsum[r] += __shfl_xor(rsum[r], d);
            #pragma unroll
            for (int r=0;r<4;++r) l_i[sub][r] = l_i[sub][r]*alpha[r] + rsum[r];
            // P -> LDS, swizzled (own wave's 16 rows; per-wave DS order)
            #pragma unroll
            for (int st=0;st<8;++st)
              #pragma unroll
              for (int r=0;r<4;++r){
                int prow = wv*16 + quad*4 + r;
                Ps[prow*128 + ((st*16 + l15) ^ (((quad*4+r)&7)<<3))] = f2b(sc[st][r]);
              }
            #pragma unroll
            for (int d=0;d<4;++d)
              #pragma unroll
              for (int r=0;r<4;++r) o[sub][d][r] = o[sub][d][r]*alpha[r];

            // PV: O[q][d] += P[q][0..127] @ V^T[d][0..127]
            bf16x8 ap[4];
            #pragma unroll
            for (int kch=0;kch<4;++kch)
                ap[kch] = *(const bf16x8*)(&Ps[(wv*16 + l15)*128 + ((kch*32 + quad*8) ^ xsw)]);
            #pragma unroll
            for (int dtile=0;dtile<4;++dtile){
                #pragma unroll
                for (int kch=0;kch<4;++kch){
                    bf16x8 bv_ = *(const bf16x8*)(&Vc[(dtile*16+l15)*128 + ((kch*32 + quad*8) ^ xsw)]);
                    o[sub][dtile] = __builtin_amdgcn_mfma_f32_16x16x32_bf16(ap[kch], bv_, o[sub][dtile], 0,0,0);
                }
            }
        }

        __builtin_amdgcn_s_barrier();       // all waves done reading buf cur
    }
    #pragma unroll
    for (int sub=0; sub<2; ++sub)
      #pragma unroll
      for (int r=0;r<4;++r){
        float inv = 1.f/l_i[sub][r];
        int gm = q0 + wv*32 + sub*16 + quad*4 + r;
        #pragma unroll
        for (int dtile=0;dtile<4;++dtile)
            attn[baseo + (size_t)gm*DMODEL + dtile*16 + l15] = f2b(o[sub][dtile][r]*inv);
      }
}

// ---------------- depthwise causal conv(4) + bias + silu -------------------
__global__ __launch_bounds__(256) void conv_silu(
    const unsigned short* __restrict__ xr, const float* __restrict__ cw,
    const float* __restrict__ cb, unsigned short* __restrict__ xm2)
{
    int idx = blockIdx.x*256 + threadIdx.x;
    int r  = idx >> 10;
    int c2 = (idx & 1023)*2;
    int s  = r & (SEQ-1);
    float4 w0 = *(const float4*)(cw + c2*4);
    float4 w1 = *(const float4*)(cw + (c2+1)*4);
    float w0a[4] = {w0.x,w0.y,w0.z,w0.w};
    float w1a[4] = {w1.x,w1.y,w1.z,w1.w};
    float a0 = cb[c2], a1 = cb[c2+1];
    const unsigned short* xrow = xr + (size_t)r*DFF + c2;
    #pragma unroll
    for (int j=0;j<4;++j){
        int sp = s - 3 + j;
        if (sp >= 0){
            int off = (j-3)*DFF;
            unsigned int u = *(const unsigned int*)(xrow + off);
            a0 += w0a[j]*b2f(u & 0xffff);
            a1 += w1a[j]*b2f(u >> 16);
        }
    }
    float s0 = a0 * __builtin_amdgcn_rcpf(1.f + __expf(-a0));
    float s1 = a1 * __builtin_amdgcn_rcpf(1.f + __expf(-a1));
    unsigned int op = (unsigned int)f2b(s0) | ((unsigned int)f2b(s1) << 16);
    *(unsigned int*)(xm2 + (size_t)r*DINNER + c2) = op;
}

// ---------------- xdbl = xm2 @ xp_w + xp_b, written as {b,c+1} pairs -------
__global__ __launch_bounds__(256) void xp_gemm(
    const unsigned short* __restrict__ xm2, const float* __restrict__ w,
    const float* __restrict__ bias, float* __restrict__ xdbl)
{
    int tid = threadIdx.x;
    int lr = tid >> 5, n = tid & 31;
    int row = blockIdx.x*8 + lr;
    const unsigned short* ar = xm2 + (size_t)row*DINNER;
    float acc = bias[n];
    #pragma unroll 4
    for (int k2 = 0; k2 < DINNER; k2 += 2){
        unsigned int u = *(const unsigned int*)(ar + k2);
        acc += b2f(u & 0xffff)*w[k2*32 + n] + b2f(u >> 16)*w[(k2+1)*32 + n];
    }
    if (n >= 16) acc += 1.f;                // c-columns carry +1 for scan's u
    int nc = (n < 16) ? 2*n : 2*(n-16)+1;   // interleave: {b_i,c_i} adjacent
    xdbl[(size_t)row*32 + nc] = acc;
}

// ---------------- sequential scan: packed-f16 dot2 + register bc banks -----
// h_{t+1}[i] = tanh(sum_j exp(dtp*A[i][j]) h_t[j]) + b_t[i]*h_t[i] + c_t[i]
// Weights pre-scaled by 2*log2e: x2 = sum (W') h, e^(2s) = exp2(x2),
// tanh = 1 - 2/(e^(2s)+1); h' = fma(-2, rcp(e2+1), (b*h + (c+1))).
// Chained 2x4 fdot2 (R10 form): accumulate is free inside dot2; minimal
// instruction count wins in this 1-wave/SIMD kernel (R11 tree regressed 47%).
__device__ __forceinline__ float scan_step_dot(float h, const f16x2 (&Wp)[8],
                                               float bv, float cv)
{
    float rr = dppf<0x121>(h);
    f16x2 p0 = __builtin_amdgcn_cvt_pkrtz(h, rr);
    f16x2 p1 = dpp_h2<0x122>(p0);
    f16x2 p2 = dpp_h2<0x124>(p0);
    f16x2 p3 = dpp_h2<0x126>(p0);
    f16x2 p4 = dpp_h2<0x128>(p0);
    f16x2 p5 = dpp_h2<0x12a>(p0);
    f16x2 p6 = dpp_h2<0x12c>(p0);
    f16x2 p7 = dpp_h2<0x12e>(p0);
    float a0 = hdot2(Wp[0], p0, 0.f);
    a0 = hdot2(Wp[1], p1, a0);
    a0 = hdot2(Wp[2], p2, a0);
    a0 = hdot2(Wp[3], p3, a0);
    float a1 = hdot2(Wp[4], p4, 0.f);
    a1 = hdot2(Wp[5], p5, a1);
    a1 = hdot2(Wp[6], p6, a1);
    a1 = hdot2(Wp[7], p7, a1);
    float u  = fmaf(bv, h, cv);                // cv already includes +1
    float e2 = exp_2s(a0 + a1);
    float r  = __builtin_amdgcn_rcpf(e2 + 1.f);
    return fmaf(-2.f, r, u);
}

__device__ __forceinline__ void load_bank(float2 (&bk)[16], const float* src){
    #pragma unroll
    for (int j=0;j<16;++j) bk[j] = *(const float2*)(src + (size_t)j*32);
}

__device__ __forceinline__ void compute16(const float2 (&bk)[16],
                                          const f16x2 (&Wf)[16][8],
                                          float& hn, float* hp, int lane)
{
    float h0s=0.f, h1s=0.f, h2s=0.f;
    #pragma unroll
    for (int j=0;j<16;++j){
        // global t = blk*16 + j -> phase t%16 == j (static weight index)
        hn = scan_step_dot(hn, Wf[j], bk[j].x, bk[j].y);
        if ((j&3)==0)      h0s = hn;
        else if ((j&3)==1) h1s = hn;
        else if ((j&3)==2) h2s = hn;
        else if (lane < 16){
            float4 o4 = {h0s, h1s, h2s, hn};
            *(float4*)(hp + j - 3) = o4;
        }
    }
}

__global__ __launch_bounds__(128,1) void scan_k(
    const float* __restrict__ xdbl, const float* __restrict__ dt,
    const float* __restrict__ A, float* __restrict__ hsT)
{
    int tid = threadIdx.x;
    int lane = tid & 63;
    int b = tid >> 6;
    int i = lane & 15;

    // probe: identical DPP fan applied to lane index -> actual source lanes.
    // pair j of the packed fan covers sources (sj[j], tj[j]).
    int c1 = dppi<0x121>(i);
    int sj[8], tj[8];
    sj[0] = i;               tj[0] = c1;
    sj[1] = dppi<0x122>(i);  tj[1] = dppi<0x122>(c1);
    sj[2] = dppi<0x124>(i);  tj[2] = dppi<0x124>(c1);
    sj[3] = dppi<0x126>(i);  tj[3] = dppi<0x126>(c1);
    sj[4] = dppi<0x128>(i);  tj[4] = dppi<0x128>(c1);
    sj[5] = dppi<0x12a>(i);  tj[5] = dppi<0x12a>(c1);
    sj[6] = dppi<0x12c>(i);  tj[6] = dppi<0x12c>(c1);
    sj[7] = dppi<0x12e>(i);  tj[7] = dppi<0x12e>(c1);

    // packed-f16 weight table: 16 phases x 8 pairs = 128 VGPRs
    f16x2 Wf[16][8];
    #pragma unroll
    for (int p=0;p<16;++p){
        float dtp = __expf(dt[p]);
        #pragma unroll
        for (int jj=0;jj<8;++jj){
            float w0 = W_SCALE*__expf(dtp * A[i*16 + sj[jj]]);
            float w1 = W_SCALE*__expf(dtp * A[i*16 + tj[jj]]);
            Wf[p][jj] = __builtin_amdgcn_cvt_pkrtz(w0, w1);
        }
    }

    // b/c stream: global -> 2x16 float2 register banks, 16-step prefetch lead
    const float* src = xdbl + (size_t)(b*SEQ)*32 + 2*i;
    float* hp = hsT + (size_t)(b*16 + i)*SEQ;
    float2 bA[16], bB[16];
    load_bank(bA, src);
    float hn = 0.f;
    for (int bp = 0; bp < 64; ++bp){
        int t0 = bp*32;
        load_bank(bB, src + (size_t)(t0+16)*32);
        compute16(bA, Wf, hn, hp + t0, lane);
        int t2 = (bp < 63) ? (t0 + 32) : 0;      // last iter: dummy reload of blk 0
        load_bank(bA, src + (size_t)t2*32);
        compute16(bB, Wf, hn, hp + t0 + 16, lane);
    }
}

// ---------------- y = repeat(hsT,128) + res (bf16) -------------------------
__global__ __launch_bounds__(256) void y_assemble(
    const float* __restrict__ hsT, const unsigned short* __restrict__ xr,
    unsigned short* __restrict__ y)
{
    int idx = blockIdx.x*256 + threadIdx.x;
    int r = idx >> 10;
    int c2 = (idx & 1023)*2;
    int bb = r >> 11, s = r & (SEQ-1);
    unsigned int u = *(const unsigned int*)(xr + (size_t)r*DFF + DINNER + c2);
    float h0 = hsT[(size_t)(bb*16 + (c2 >> 7))*SEQ + s];
    float y0 = h0 + b2f(u & 0xffff);
    float y1 = h0 + b2f(u >> 16);
    *(unsigned int*)(y + (size_t)r*DINNER + c2) =
        (unsigned int)f2b(y0) | ((unsigned int)f2b(y1) << 16);
}

// ---------------------------------------------------------------------------
extern "C" void kernel_launch(void* const* d_in, const int* in_sizes, int n_in,
                              void* d_out, int out_size, void* d_ws, size_t ws_size,
                              hipStream_t stream)
{
    (void)in_sizes; (void)n_in; (void)out_size; (void)ws_size;
    const float* x     = (const float*)d_in[0];
    const float* ln1_g = (const float*)d_in[1];
    const float* ln1_b = (const float*)d_in[2];
    const float* Wq    = (const float*)d_in[3];
    const float* bq    = (const float*)d_in[4];
    const float* Wk    = (const float*)d_in[5];
    const float* bk    = (const float*)d_in[6];
    const float* Wv    = (const float*)d_in[7];
    const float* bv    = (const float*)d_in[8];
    const float* Wo    = (const float*)d_in[9];
    const float* bo    = (const float*)d_in[10];
    const float* ln2_g = (const float*)d_in[11];
    const float* ln2_b = (const float*)d_in[12];
    const float* in_w  = (const float*)d_in[13];
    const float* in_b  = (const float*)d_in[14];
    const float* conv_w= (const float*)d_in[15];
    const float* conv_b= (const float*)d_in[16];
    const float* xp_w  = (const float*)d_in[17];
    const float* xp_b  = (const float*)d_in[18];
    const float* dt    = (const float*)d_in[19];
    const float* A     = (const float*)d_in[20];
    const float* out_w = (const float*)d_in[22];
    const float* out_b = (const float*)d_in[23];
    const float* ln3_g = (const float*)d_in[24];
    const float* ln3_b = (const float*)d_in[25];
    const float* fc1_w = (const float*)d_in[26];
    const float* fc1_b = (const float*)d_in[27];
    const float* fc2_w = (const float*)d_in[28];
    const float* fc2_b = (const float*)d_in[29];

    char* ws = (char*)d_ws;
    const size_t MB = 1ull << 20;
    unsigned short* qkvT = (unsigned short*)(ws + 0*MB);   // WqT|WkT|WvT, 6MB
    unsigned short* WoT  = (unsigned short*)(ws + 6*MB);
    unsigned short* inT  = (unsigned short*)(ws + 8*MB);
    unsigned short* outT = (unsigned short*)(ws + 16*MB);
    unsigned short* f1T  = (unsigned short*)(ws + 20*MB);
    unsigned short* f2T  = (unsigned short*)(ws + 28*MB);
    unsigned short* hbf  = (unsigned short*)(ws + 36*MB);  // also vT window
    float*          x2   = (float*)(ws + 44*MB);
    float*          x3   = (float*)(ws + 60*MB);
    unsigned short* qkv  = (unsigned short*)(ws + 76*MB);  // 24MB fused QKV
    unsigned short* attnb= (unsigned short*)(ws + 100*MB);
    unsigned short* xr   = (unsigned short*)(ws + 76*MB);  // reuse after attn
    unsigned short* ffn  = (unsigned short*)(ws + 76*MB);  // reuse after y
    unsigned short* xm2  = (unsigned short*)(ws + 108*MB);
    unsigned short* yb   = (unsigned short*)(ws + 108*MB); // reuse after xp
    float*          xdbl = (float*)(ws + 124*MB);
    float*          hsb  = (float*)(ws + 124*MB + 512*1024);
    float*          bqkv = (float*)(ws + 125*MB);

    dim3 blk(256);
    transpose_cast<<<dim3(16,16), blk, 0, stream>>>(Wq, qkvT,              1024, 1024);
    transpose_cast<<<dim3(16,16), blk, 0, stream>>>(Wk, qkvT + 1024*1024,  1024, 1024);
    transpose_cast<<<dim3(16,16), blk, 0, stream>>>(Wv, qkvT + 2*1024*1024,1024, 1024);
    transpose_cast<<<dim3(16,16), blk, 0, stream>>>(Wo, WoT, 1024, 1024);
    transpose_cast<<<dim3(64,16), blk, 0, stream>>>(in_w, inT, 1024, 4096);
    transpose_cast<<<dim3(16,32), blk, 0, stream>>>(out_w, outT, 2048, 1024);
    transpose_cast<<<dim3(64,16), blk, 0, stream>>>(fc1_w, f1T, 1024, 4096);
    transpose_cast<<<dim3(16,64), blk, 0, stream>>>(fc2_w, f2T, 4096, 1024);
    concat_bias<<<12, blk, 0, stream>>>(bq, bk, bv, bqkv);

    layernorm_bf16<<<MROWS, blk, 0, stream>>>(x, ln1_g, ln1_b, hbf);
    gemm_bt<128,1,0,0><<<dim3(24,32), blk, 0, stream>>>(hbf, qkvT, bqkv, nullptr, qkv, QKVLD, 1024);
    transpose_v<<<dim3(32,32), blk, 0, stream>>>(qkv, hbf);   // vT in hbf window
    attn_flash<<<dim3(16,32), blk, 0, stream>>>(qkv, hbf, attnb);
    gemm_bt<64,0,1,0><<<dim3(16,32), blk, 0, stream>>>(attnb, WoT, bo, x, x2, 1024, 1024);
    layernorm_bf16<<<MROWS, blk, 0, stream>>>(x2, ln2_g, ln2_b, hbf);
    gemm_bt<128,1,0,0><<<dim3(32,32), blk, 0, stream>>>(hbf, inT, in_b, nullptr, xr, 4096, 1024);
    conv_silu<<<16384, blk, 0, stream>>>(xr, conv_w, conv_b, xm2);
    xp_gemm<<<512, blk, 0, stream>>>(xm2, xp_w, xp_b, xdbl);
    scan_k<<<1, dim3(128), 0, stream>>>(xdbl, dt, A, hsb);
    y_assemble<<<16384, blk, 0, stream>>>(hsb, xr, yb);
    gemm_bt<64,0,1,0><<<dim3(16,32), blk, 0, stream>>>(yb, outT, out_b, x2, x3, 1024, 2048);
    layernorm_bf16<<<MROWS, blk, 0, stream>>>(x3, ln3_g, ln3_b, hbf);
    gemm_bt<128,1,0,1><<<dim3(32,32), blk, 0, stream>>>(hbf, f1T, fc1_b, nullptr, ffn, 4096, 1024);
    gemm_bt<64,0,1,0><<<dim3(16,32), blk, 0, stream>>>(ffn, f2T, fc2_b, x3, (float*)d_out, 1024, 4096);
}

// Round 8
// 850.079 us; speedup vs baseline: 1.0492x; 1.0103x over previous
//
#include <hip/hip_runtime.h>
#include <hip/hip_bf16.h>

// ---------------------------------------------------------------------------
// R14 changes vs R13:
//  * scan_k: Wf weight table (128 VGPRs) moved to LDS. VGPR_Count=104 vs
//    >=192 live state implied the table was scratch-spilled (scratch hits
//    L1/L2, invisible in FETCH_SIZE). Layout [phase][i-row stride 12 dw]
//    -> per step 2x ds_read_b128, 16B aligned, 2-way bank alias only
//    (i,i+8) = free per m136; 4 lane-groups broadcast. Setup distributed
//    8 groups x 2 phases; one __syncthreads added. Dot-chain untouched
//    (R11 lesson: don't perturb it).
//  * transpose_cast4 / transpose_cast2: 4x 1024^2 and 2x 1024x4096 weight
//    transposes merged into single dispatches (9 -> 6 preamble launches).
//  * attn_flash / gemm_bt unchanged from R13 (858.9us).
// ---------------------------------------------------------------------------

#define SEQ     2048
#define BATCH   2
#define MROWS   4096      // BATCH*SEQ
#define DMODEL  1024
#define DINNER  2048
#define DFF     4096
#define QKVLD   3072

typedef __attribute__((ext_vector_type(8))) short bf16x8;
typedef __attribute__((ext_vector_type(4))) float f32x4;
typedef __attribute__((ext_vector_type(2))) __fp16 f16x2;

__device__ __forceinline__ unsigned short f2b(float x){
    __hip_bfloat16 h = __float2bfloat16(x);
    return *reinterpret_cast<unsigned short*>(&h);
}
__device__ __forceinline__ float b2f(unsigned short u){
    __hip_bfloat16 h;
    *reinterpret_cast<unsigned short*>(&h) = u;
    return __bfloat162float(h);
}
__device__ __forceinline__ float gelu_f(float v){
    float u = 0.7978845608f*(v + 0.044715f*v*v*v);
    float e = __expf(2.f*u);
    float th = 1.f - 2.f*__builtin_amdgcn_rcpf(e + 1.f);
    return 0.5f*v*(1.f + th);
}
__device__ __forceinline__ void gload16(const unsigned short* g, unsigned short* l){
    __builtin_amdgcn_global_load_lds(
        (const __attribute__((address_space(1))) void*)g,
        (__attribute__((address_space(3))) void*)l, 16, 0, 0);
}
template<int CTRL>
__device__ __forceinline__ float dppf(float x){
    int r = __builtin_amdgcn_mov_dpp(__builtin_bit_cast(int, x), CTRL, 0xf, 0xf, false);
    return __builtin_bit_cast(float, r);
}
template<int CTRL>
__device__ __forceinline__ int dppi(int x){
    return __builtin_amdgcn_mov_dpp(x, CTRL, 0xf, 0xf, false);
}
template<int CTRL>
__device__ __forceinline__ f16x2 dpp_h2(f16x2 x){
    int r = __builtin_amdgcn_mov_dpp(__builtin_bit_cast(int, x), CTRL, 0xf, 0xf, false);
    return __builtin_bit_cast(f16x2, r);
}

#if __has_builtin(__builtin_amdgcn_exp2f)
#define W_SCALE 2.8853900817779268f   /* 2*log2(e): x2 = 2*log2e*s, e^(2s)=2^x2 */
__device__ __forceinline__ float exp_2s(float x){ return __builtin_amdgcn_exp2f(x); }
#else
#define W_SCALE 2.0f
__device__ __forceinline__ float exp_2s(float x){ return __expf(x); }
#endif

__device__ __forceinline__ float hdot2(f16x2 a, f16x2 b, float c){
#if __has_builtin(__builtin_amdgcn_fdot2)
    return __builtin_amdgcn_fdot2(a, b, c, false);
#else
    return c + (float)a[0]*(float)b[0] + (float)a[1]*(float)b[1];
#endif
}
__device__ __forceinline__ f16x2 u2h(unsigned u){ return __builtin_bit_cast(f16x2, u); }

// ---------------- transpose + cast: W (KxN f32) -> Wt (NxK bf16) ----------
__device__ __forceinline__ void tc_body(
    const float* __restrict__ W, unsigned short* __restrict__ Wt, int K, int N)
{
    __shared__ float t[64*65];
    int n0 = blockIdx.x*64, k0 = blockIdx.y*64;
    int c = threadIdx.x & 63, r0 = threadIdx.x >> 6;
    #pragma unroll
    for (int rr = 0; rr < 64; rr += 4)
        t[(rr+r0)*65 + c] = W[(size_t)(k0+rr+r0)*N + n0 + c];
    __syncthreads();
    #pragma unroll
    for (int rr = 0; rr < 64; rr += 4)
        Wt[(size_t)(n0+rr+r0)*K + k0 + c] = f2b(t[c*65 + rr + r0]);
}

__global__ __launch_bounds__(256) void transpose_cast(
    const float* __restrict__ W, unsigned short* __restrict__ Wt, int K, int N)
{
    tc_body(W, Wt, K, N);
}

__global__ __launch_bounds__(256) void transpose_cast4(
    const float* __restrict__ W0, const float* __restrict__ W1,
    const float* __restrict__ W2, const float* __restrict__ W3,
    unsigned short* __restrict__ T0, unsigned short* __restrict__ T1,
    unsigned short* __restrict__ T2, unsigned short* __restrict__ T3,
    int K, int N)
{
    const float* W; unsigned short* Wt;
    switch (blockIdx.z){
        case 0:  W = W0; Wt = T0; break;
        case 1:  W = W1; Wt = T1; break;
        case 2:  W = W2; Wt = T2; break;
        default: W = W3; Wt = T3; break;
    }
    tc_body(W, Wt, K, N);
}

__global__ __launch_bounds__(256) void transpose_cast2(
    const float* __restrict__ W0, const float* __restrict__ W1,
    unsigned short* __restrict__ T0, unsigned short* __restrict__ T1,
    int K, int N)
{
    const float* W = blockIdx.z ? W1 : W0;
    unsigned short* Wt = blockIdx.z ? T1 : T0;
    tc_body(W, Wt, K, N);
}

// ---------------- concat 3 bias vectors --------------------------------
__global__ __launch_bounds__(256) void concat_bias(
    const float* __restrict__ b0, const float* __restrict__ b1,
    const float* __restrict__ b2, float* __restrict__ o)
{
    int t = blockIdx.x*256 + threadIdx.x;
    float v = (t < 1024) ? b0[t] : (t < 2048 ? b1[t-1024] : b2[t-2048]);
    o[t] = v;
}

// ---------------- layernorm row=1024, f32 in -> bf16 out ------------------
__global__ __launch_bounds__(256) void layernorm_bf16(
    const float* __restrict__ x, const float* __restrict__ g,
    const float* __restrict__ b, unsigned short* __restrict__ out)
{
    int row = blockIdx.x;
    const float4* xr = (const float4*)(x + (size_t)row*DMODEL);
    int tid = threadIdx.x;
    float4 xv = xr[tid];
    float s  = xv.x + xv.y + xv.z + xv.w;
    float ss = xv.x*xv.x + xv.y*xv.y + xv.z*xv.z + xv.w*xv.w;
    #pragma unroll
    for (int d = 32; d > 0; d >>= 1){ s += __shfl_xor(s,d); ss += __shfl_xor(ss,d); }
    __shared__ float sm[8];
    int wv = tid>>6, ln = tid&63;
    if (ln == 0){ sm[wv] = s; sm[4+wv] = ss; }
    __syncthreads();
    s  = sm[0]+sm[1]+sm[2]+sm[3];
    ss = sm[4]+sm[5]+sm[6]+sm[7];
    float mean = s*(1.f/DMODEL);
    float var  = ss*(1.f/DMODEL) - mean*mean;
    float rstd = rsqrtf(var + 1e-5f);
    float4 gv = ((const float4*)g)[tid];
    float4 bv = ((const float4*)b)[tid];
    ushort4 o;
    o.x = f2b((xv.x-mean)*rstd*gv.x + bv.x);
    o.y = f2b((xv.y-mean)*rstd*gv.y + bv.y);
    o.z = f2b((xv.z-mean)*rstd*gv.z + bv.z);
    o.w = f2b((xv.w-mean)*rstd*gv.w + bv.w);
    ((ushort4*)(out + (size_t)row*DMODEL))[tid] = o;
}

// ---------------- GEMM: C[M,N] = act(A[M,K] @ Bt[N,K]^T + bias) (+res) ----
// 128xBN tile, 4 waves (2x2), wave does 64x(BN/2). BK=64. global_load_lds.
template<int BN, int OUT_BF16, int HAS_RES, int ACT>
__global__ __launch_bounds__(256,3) void gemm_bt(
    const unsigned short* __restrict__ A, const unsigned short* __restrict__ Bt,
    const float* __restrict__ bias, const float* __restrict__ res,
    void* __restrict__ outp, int Ndim, int Kdim)
{
    constexpr int NT = BN/32;               // n-tiles per wave
    constexpr int BROWS = BN/32;            // B staging iters per wave (8 rows each)
    __shared__ unsigned short As[128*64];   // unpadded: required by global_load_lds
    __shared__ unsigned short Bs[BN*64];
    int tid = threadIdx.x;
    int lane = tid & 63, wv = tid >> 6;
    int l15 = lane & 15, quad = lane >> 4;
    int m0 = blockIdx.y*128, n0 = blockIdx.x*BN;
    int mo = (wv>>1)*64, no = (wv&1)*(BN/2);
    int rsub = (lane >> 3);          // 0..7
    int cc8  = (lane & 7)*8;         // element col within 64
    f32x4 zz = {0.f,0.f,0.f,0.f};
    f32x4 acc[4][NT];
    #pragma unroll
    for (int i=0;i<4;++i)
      #pragma unroll
      for (int j=0;j<NT;++j) acc[i][j] = zz;

    for (int k0 = 0; k0 < Kdim; k0 += 64){
        const unsigned short* Ab = A  + (size_t)(m0 + wv*32 + rsub)*Kdim + k0 + cc8;
        const unsigned short* Bb = Bt + (size_t)(n0 + wv*(BN/4) + rsub)*Kdim + k0 + cc8;
        #pragma unroll
        for (int i=0;i<4;++i)
            gload16(Ab + (size_t)(i*8)*Kdim, &As[(wv*32 + i*8)*64]);
        #pragma unroll
        for (int i=0;i<BROWS;++i)
            gload16(Bb + (size_t)(i*8)*Kdim, &Bs[(wv*(BN/4) + i*8)*64]);
        __syncthreads();
        #pragma unroll
        for (int kc=0;kc<2;++kc){
            bf16x8 af[4], bfr[NT];
            #pragma unroll
            for (int t=0;t<4;++t)
                af[t]  = *(const bf16x8*)(&As[(mo + t*16 + l15)*64 + kc*32 + quad*8]);
            #pragma unroll
            for (int t=0;t<NT;++t)
                bfr[t] = *(const bf16x8*)(&Bs[(no + t*16 + l15)*64 + kc*32 + quad*8]);
            #pragma unroll
            for (int mt=0;mt<4;++mt)
              #pragma unroll
              for (int nt=0;nt<NT;++nt)
                acc[mt][nt] = __builtin_amdgcn_mfma_f32_16x16x32_bf16(af[mt], bfr[nt], acc[mt][nt], 0,0,0);
        }
        __syncthreads();
    }
    #pragma unroll
    for (int mt=0;mt<4;++mt){
      #pragma unroll
      for (int nt=0;nt<NT;++nt){
        int gn = n0 + no + nt*16 + l15;
        float bval = bias[gn];
        #pragma unroll
        for (int r=0;r<4;++r){
            int gm = m0 + mo + mt*16 + quad*4 + r;
            size_t off = (size_t)gm*Ndim + gn;
            float v = acc[mt][nt][r] + bval;
            if constexpr (HAS_RES) v += res[off];
            if constexpr (ACT == 1) v = gelu_f(v);
            if constexpr (OUT_BF16) ((unsigned short*)outp)[off] = f2b(v);
            else                    ((float*)outp)[off] = v;
        }
      }
    }
}

// ---------------- V pre-transpose: qkv v-slice -> vT[bh][d=64][SEQ] -------
__global__ __launch_bounds__(256) void transpose_v(
    const unsigned short* __restrict__ qkv, unsigned short* __restrict__ vT)
{
    __shared__ unsigned int t[64*33];   // [k-row][d-pair], pad 33 -> conflict-free
    int bh = blockIdx.y;
    int t0 = blockIdx.x*64;
    int tid = threadIdx.x;
    const size_t base = (size_t)(bh>>4)*SEQ*QKVLD + (size_t)(bh&15)*64 + 2*DMODEL;
    #pragma unroll
    for (int i=0;i<2;++i){
        int idx = tid + i*256;          // 0..511
        int r = idx>>3, cc = idx&7;     // k-row 0..63, d-chunk
        uint4 vv = *(const uint4*)(qkv + base + (size_t)(t0+r)*QKVLD + cc*8);
        t[r*33 + cc*4 + 0] = vv.x;
        t[r*33 + cc*4 + 1] = vv.y;
        t[r*33 + cc*4 + 2] = vv.z;
        t[r*33 + cc*4 + 3] = vv.w;
    }
    __syncthreads();
    unsigned short* outb = vT + (size_t)bh*64*SEQ + t0;
    #pragma unroll
    for (int i=0;i<2;++i){
        int idx = tid + i*256;
        int d = idx>>3, cc = idx&7;     // d-row 0..63, k-chunk
        int sh = (d&1)*16, dp = d>>1;
        unsigned int o4[4];
        #pragma unroll
        for (int j2=0;j2<4;++j2){
            unsigned int ua = t[(cc*8 + 2*j2    )*33 + dp];
            unsigned int ub = t[(cc*8 + 2*j2 + 1)*33 + dp];
            unsigned int ha = (ua >> sh) & 0xffff;
            unsigned int hb = (ub >> sh) & 0xffff;
            o4[j2] = ha | (hb << 16);
        }
        *(uint4*)(outb + (size_t)d*SEQ + cc*8) = *(uint4*)o4;
    }
}

// ---------------- flash attention, causal, 16 heads of 64 ------------------
// q/k from fused qkv (row stride QKVLD); v pre-transposed in vT.
// q-tile 128 (wave owns 32 rows = 2 sequential 16-row subs), KV tile 128,
// double-buffered global_load_lds staging with counted vmcnt across raw
// barriers; unpadded LDS, both-sides XOR swizzle everywhere.
__device__ __forceinline__ void stage_kv(
    const unsigned short* __restrict__ k, const unsigned short* __restrict__ vTb,
    int t0, unsigned short* Ks, unsigned short* Vt, int wv, int lane)
{
    #pragma unroll
    for (int p=0;p<4;++p){
        int c0 = p*256 + wv*64;         // wave-uniform chunk base
        int c  = c0 + lane;             // this lane's chunk
        int kr = c>>3, kc = (c&7)*8;    // K: row 0..127, col-chunk
        int vr = c>>4, vc = (c&15)*8;   // V: row 0..63,  col-chunk
        gload16(k   + (size_t)(t0+kr)*QKVLD + (kc ^ ((kr&7)<<3)), Ks + c0*8);
        gload16(vTb + (size_t)vr*SEQ + t0 +   (vc ^ ((vr&7)<<3)), Vt + c0*8);
    }
}

__global__ __launch_bounds__(256,2) void attn_flash(
    const unsigned short* __restrict__ qkv, const unsigned short* __restrict__ vT,
    unsigned short* __restrict__ attn)
{
    __shared__ unsigned short Ks[2][128*64];  // [buf][k][d], col-swizzled
    __shared__ unsigned short Vt[2][64*128];  // [buf][d][k], col-swizzled
    __shared__ unsigned short Ps[64*128];     // [q-sub][k], col-swizzled
    int bh = blockIdx.y;
    int qt = (int)gridDim.x - 1 - (int)blockIdx.x;   // heavy blocks first
    int q0 = qt*128;
    int tid = threadIdx.x, wv = tid>>6, lane = tid&63;
    int l15 = lane&15, quad = lane>>4;
    int xsw = (l15&7)<<3;                   // read-side XOR (row&7 == l15&7)
    const size_t basei = (size_t)(bh>>4)*SEQ*QKVLD + (size_t)(bh&15)*64;
    const unsigned short* q = qkv + basei;
    const unsigned short* k = qkv + basei + DMODEL;
    const unsigned short* vTb = vT + (size_t)bh*64*SEQ;
    const size_t baseo = (size_t)(bh>>4)*SEQ*DMODEL + (size_t)(bh&15)*64;

    int nkt = qt + 1;   // number of 128-wide kv tiles (causal)

    stage_kv(k, vTb, 0, Ks[0], Vt[0], wv, lane);

    // Q fragments directly from global (no LDS round-trip); 2 subs of 16 rows
    bf16x8 aq[2][2];
    #pragma unroll
    for (int s=0;s<2;++s){
        int qr = q0 + wv*32 + s*16 + l15;
        aq[s][0] = *(const bf16x8*)(q + (size_t)qr*QKVLD + quad*8);
        aq[s][1] = *(const bf16x8*)(q + (size_t)qr*QKVLD + 32 + quad*8);
    }

    float m_i[2][4], l_i[2][4];
    f32x4 zz = {0.f,0.f,0.f,0.f};
    f32x4 o[2][4];
    #pragma unroll
    for (int s=0;s<2;++s)
      #pragma unroll
      for (int r=0;r<4;++r){ m_i[s][r] = -__builtin_inff(); l_i[s][r] = 0.f; }
    #pragma unroll
    for (int s=0;s<2;++s)
      #pragma unroll
      for (int d=0;d<4;++d) o[s][d] = zz;

    const float SCL = 0.1803368801111137f;   // 0.125 * log2(e): exp2-domain softmax

    asm volatile("s_waitcnt vmcnt(0)" ::: "memory");   // tile 0 + Q landed
    __builtin_amdgcn_s_barrier();

    for (int kt = 0; kt < nkt; ++kt){
        int t0 = kt*128;
        bool diagt = (kt == qt);
        int cur = kt & 1;
        const unsigned short* Kc = Ks[cur];
        const unsigned short* Vc = Vt[cur];

        if (kt + 1 < nkt){
            stage_kv(k, vTb, t0 + 128, Ks[cur^1], Vt[cur^1], wv, lane);
            // 8 prefetch loads in flight; wait for the 8 older (tile kt) only
            asm volatile("s_waitcnt vmcnt(8)" ::: "memory");
        } else {
            asm volatile("s_waitcnt vmcnt(0)" ::: "memory");
        }
        __builtin_amdgcn_sched_barrier(0);
        __builtin_amdgcn_s_barrier();       // all waves: tile kt staged

        #pragma unroll
        for (int sub=0; sub<2; ++sub){
            // QK^T: 8 sub-tiles of 16 k-cols each
            f32x4 sc[8];
            #pragma unroll
            for (int st=0;st<8;++st){
                bf16x8 b0 = *(const bf16x8*)(&Kc[(st*16+l15)*64 + ((     quad*8) ^ xsw)]);
                bf16x8 b1 = *(const bf16x8*)(&Kc[(st*16+l15)*64 + ((32 + quad*8) ^ xsw)]);
                sc[st] = __builtin_amdgcn_mfma_f32_16x16x32_bf16(aq[sub][0], b0, zz, 0,0,0);
                sc[st] = __builtin_amdgcn_mfma_f32_16x16x32_bf16(aq[sub][1], b1, sc[st], 0,0,0);
            }
            int qrb = q0 + wv*32 + sub*16 + quad*4;
            float mrow[4];
            #pragma unroll
            for (int r=0;r<4;++r) mrow[r] = -__builtin_inff();
            #pragma unroll
            for (int st=0;st<8;++st)
              #pragma unroll
              for (int r=0;r<4;++r){
                float svv = sc[st][r]*SCL;
                if (diagt && (t0 + st*16 + l15 > qrb + r))
                    svv = -__builtin_inff();
                sc[st][r] = svv;
                mrow[r] = fmaxf(mrow[r], svv);
              }
            #pragma unroll
            for (int d=1; d<16; d<<=1)
              #pragma unroll
              for (int r=0;r<4;++r) mrow[r] = fmaxf(mrow[r], __shfl_xor(mrow[r], d));
            float alpha[4], rsum[4];
            #pragma unroll
            for (int r=0;r<4;++r){
                float mn = fmaxf(m_i[sub][r], mrow[r]);
                alpha[r] = exp_2s(m_i[sub][r] - mn);
                m_i[sub][r] = mn;
            }
            #pragma unroll
            for (int st=0;st<8;++st)
              #pragma unroll
              for (int r=0;r<4;++r) sc[st][r] = exp_2s(sc[st][r] - m_i[sub][r]);
            #pragma unroll
            for (int r=0;r<4;++r){
                rsum[r] = ((sc[0][r]+sc[1][r])+(sc[2][r]+sc[3][r]))
                        + ((sc[4][r]+sc[5][r])+(sc[6][r]+sc[7][r]));
            }
            #pragma unroll
            for (int d=1; d<16; d<<=1)
              #pragma unroll
              for (int r=0;r<4;++r) rsum[r] += __shfl_xor(rsum[r], d);
            #pragma unroll
            for (int r=0;r<4;++r) l_i[sub][r] = l_i[sub][r]*alpha[r] + rsum[r];
            // P -> LDS, swizzled (own wave's 16 rows; per-wave DS order)
            #pragma unroll
            for (int st=0;st<8;++st)
              #pragma unroll
              for (int r=0;r<4;++r){
                int prow = wv*16 + quad*4 + r;
                Ps[prow*128 + ((st*16 + l15) ^ (((quad*4+r)&7)<<3))] = f2b(sc[st][r]);
              }
            #pragma unroll
            for (int d=0;d<4;++d)
              #pragma unroll
              for (int r=0;r<4;++r) o[sub][d][r] = o[sub][d][r]*alpha[r];

            // PV: O[q][d] += P[q][0..127] @ V^T[d][0..127]
            bf16x8 ap[4];
            #pragma unroll
            for (int kch=0;kch<4;++kch)
                ap[kch] = *(const bf16x8*)(&Ps[(wv*16 + l15)*128 + ((kch*32 + quad*8) ^ xsw)]);
            #pragma unroll
            for (int dtile=0;dtile<4;++dtile){
                #pragma unroll
                for (int kch=0;kch<4;++kch){
                    bf16x8 bv_ = *(const bf16x8*)(&Vc[(dtile*16+l15)*128 + ((kch*32 + quad*8) ^ xsw)]);
                    o[sub][dtile] = __builtin_amdgcn_mfma_f32_16x16x32_bf16(ap[kch], bv_, o[sub][dtile], 0,0,0);
                }
            }
        }

        __builtin_amdgcn_s_barrier();       // all waves done reading buf cur
    }
    #pragma unroll
    for (int sub=0; sub<2; ++sub)
      #pragma unroll
      for (int r=0;r<4;++r){
        float inv = 1.f/l_i[sub][r];
        int gm = q0 + wv*32 + sub*16 + quad*4 + r;
        #pragma unroll
        for (int dtile=0;dtile<4;++dtile)
            attn[baseo + (size_t)gm*DMODEL + dtile*16 + l15] = f2b(o[sub][dtile][r]*inv);
      }
}

// ---------------- depthwise causal conv(4) + bias + silu -------------------
__global__ __launch_bounds__(256) void conv_silu(
    const unsigned short* __restrict__ xr, const float* __restrict__ cw,
    const float* __restrict__ cb, unsigned short* __restrict__ xm2)
{
    int idx = blockIdx.x*256 + threadIdx.x;
    int r  = idx >> 10;
    int c2 = (idx & 1023)*2;
    int s  = r & (SEQ-1);
    float4 w0 = *(const float4*)(cw + c2*4);
    float4 w1 = *(const float4*)(cw + (c2+1)*4);
    float w0a[4] = {w0.x,w0.y,w0.z,w0.w};
    float w1a[4] = {w1.x,w1.y,w1.z,w1.w};
    float a0 = cb[c2], a1 = cb[c2+1];
    const unsigned short* xrow = xr + (size_t)r*DFF + c2;
    #pragma unroll
    for (int j=0;j<4;++j){
        int sp = s - 3 + j;
        if (sp >= 0){
            int off = (j-3)*DFF;
            unsigned int u = *(const unsigned int*)(xrow + off);
            a0 += w0a[j]*b2f(u & 0xffff);
            a1 += w1a[j]*b2f(u >> 16);
        }
    }
    float s0 = a0 * __builtin_amdgcn_rcpf(1.f + __expf(-a0));
    float s1 = a1 * __builtin_amdgcn_rcpf(1.f + __expf(-a1));
    unsigned int op = (unsigned int)f2b(s0) | ((unsigned int)f2b(s1) << 16);
    *(unsigned int*)(xm2 + (size_t)r*DINNER + c2) = op;
}

// ---------------- xdbl = xm2 @ xp_w + xp_b, written as {b,c+1} pairs -------
__global__ __launch_bounds__(256) void xp_gemm(
    const unsigned short* __restrict__ xm2, const float* __restrict__ w,
    const float* __restrict__ bias, float* __restrict__ xdbl)
{
    int tid = threadIdx.x;
    int lr = tid >> 5, n = tid & 31;
    int row = blockIdx.x*8 + lr;
    const unsigned short* ar = xm2 + (size_t)row*DINNER;
    float acc = bias[n];
    #pragma unroll 4
    for (int k2 = 0; k2 < DINNER; k2 += 2){
        unsigned int u = *(const unsigned int*)(ar + k2);
        acc += b2f(u & 0xffff)*w[k2*32 + n] + b2f(u >> 16)*w[(k2+1)*32 + n];
    }
    if (n >= 16) acc += 1.f;                // c-columns carry +1 for scan's u
    int nc = (n < 16) ? 2*n : 2*(n-16)+1;   // interleave: {b_i,c_i} adjacent
    xdbl[(size_t)row*32 + nc] = acc;
}

// ---------------- sequential scan: packed-f16 dot2, LDS weight table ------
// h_{t+1}[i] = tanh(sum_j exp(dtp*A[i][j]) h_t[j]) + b_t[i]*h_t[i] + c_t[i]
// Weights pre-scaled by 2*log2e: x2 = sum (W') h, e^(2s) = exp2(x2),
// tanh = 1 - 2/(e^(2s)+1); h' = fma(-2, rcp(e2+1), (b*h + (c+1))).
// Chained 2x4 fdot2 (R10 form; R11 tree regressed). Weight table lives in
// LDS ([phase][i] stride 12 dwords -> 2x ds_read_b128/step, 2-way alias
// only (i,i+8) = free) instead of 128 VGPRs that were scratch-spilled.
__device__ __forceinline__ float scan_step_lds(float h, const float* lwp,
                                               float bv, float cv)
{
    uint4 wa = *(const uint4*)(lwp);
    uint4 wb = *(const uint4*)(lwp + 4);
    float rr = dppf<0x121>(h);
    f16x2 p0 = __builtin_amdgcn_cvt_pkrtz(h, rr);
    f16x2 p1 = dpp_h2<0x122>(p0);
    f16x2 p2 = dpp_h2<0x124>(p0);
    f16x2 p3 = dpp_h2<0x126>(p0);
    f16x2 p4 = dpp_h2<0x128>(p0);
    f16x2 p5 = dpp_h2<0x12a>(p0);
    f16x2 p6 = dpp_h2<0x12c>(p0);
    f16x2 p7 = dpp_h2<0x12e>(p0);
    float a0 = hdot2(u2h(wa.x), p0, 0.f);
    a0 = hdot2(u2h(wa.y), p1, a0);
    a0 = hdot2(u2h(wa.z), p2, a0);
    a0 = hdot2(u2h(wa.w), p3, a0);
    float a1 = hdot2(u2h(wb.x), p4, 0.f);
    a1 = hdot2(u2h(wb.y), p5, a1);
    a1 = hdot2(u2h(wb.z), p6, a1);
    a1 = hdot2(u2h(wb.w), p7, a1);
    float u  = fmaf(bv, h, cv);                // cv already includes +1
    float e2 = exp_2s(a0 + a1);
    float r  = __builtin_amdgcn_rcpf(e2 + 1.f);
    return fmaf(-2.f, r, u);
}

__device__ __forceinline__ void load_bank(float2 (&bk)[16], const float* src){
    #pragma unroll
    for (int j=0;j<16;++j) bk[j] = *(const float2*)(src + (size_t)j*32);
}

__device__ __forceinline__ void compute16(const float2 (&bk)[16],
                                          const float* __restrict__ lw_i,
                                          float& hn, float* hp, int lane)
{
    float h0s=0.f, h1s=0.f, h2s=0.f;
    #pragma unroll
    for (int j=0;j<16;++j){
        // global t = blk*16 + j -> phase t%16 == j (static weight index)
        hn = scan_step_lds(hn, lw_i + j*192, bk[j].x, bk[j].y);
        if ((j&3)==0)      h0s = hn;
        else if ((j&3)==1) h1s = hn;
        else if ((j&3)==2) h2s = hn;
        else if (lane < 16){
            float4 o4 = {h0s, h1s, h2s, hn};
            *(float4*)(hp + j - 3) = o4;
        }
    }
}

__global__ __launch_bounds__(128,1) void scan_k(
    const float* __restrict__ xdbl, const float* __restrict__ dt,
    const float* __restrict__ A, float* __restrict__ hsT)
{
    __shared__ float lw[16*192];   // [phase][i*12 + jj], stride 12 dwords
    int tid = threadIdx.x;
    int lane = tid & 63;
    int b = tid >> 6;
    int i = lane & 15;

    // probe: identical DPP fan applied to lane index -> actual source lanes.
    // pair j of the packed fan covers sources (sj[j], tj[j]).
    int c1 = dppi<0x121>(i);
    int sj[8], tj[8];
    sj[0] = i;               tj[0] = c1;
    sj[1] = dppi<0x122>(i);  tj[1] = dppi<0x122>(c1);
    sj[2] = dppi<0x124>(i);  tj[2] = dppi<0x124>(c1);
    sj[3] = dppi<0x126>(i);  tj[3] = dppi<0x126>(c1);
    sj[4] = dppi<0x128>(i);  tj[4] = dppi<0x128>(c1);
    sj[5] = dppi<0x12a>(i);  tj[5] = dppi<0x12a>(c1);
    sj[6] = dppi<0x12c>(i);  tj[6] = dppi<0x12c>(c1);
    sj[7] = dppi<0x12e>(i);  tj[7] = dppi<0x12e>(c1);

    // weight table -> LDS: thread-group (tid>>4) covers 2 phases for row i
    int grp = tid >> 4;   // 0..7
    #pragma unroll
    for (int pp=0; pp<2; ++pp){
        int p = grp*2 + pp;
        float dtp = __expf(dt[p]);
        #pragma unroll
        for (int jj=0;jj<8;++jj){
            float w0 = W_SCALE*__expf(dtp * A[i*16 + sj[jj]]);
            float w1 = W_SCALE*__expf(dtp * A[i*16 + tj[jj]]);
            f16x2 pk = __builtin_amdgcn_cvt_pkrtz(w0, w1);
            lw[p*192 + i*12 + jj] = __builtin_bit_cast(float, pk);
        }
    }
    __syncthreads();

    // b/c stream: global -> 2x16 float2 register banks, 16-step prefetch lead
    const float* src = xdbl + (size_t)(b*SEQ)*32 + 2*i;
    const float* lw_i = lw + i*12;
    float* hp = hsT + (size_t)(b*16 + i)*SEQ;
    float2 bA[16], bB[16];
    load_bank(bA, src);
    float hn = 0.f;
    for (int bp = 0; bp < 64; ++bp){
        int t0 = bp*32;
        load_bank(bB, src + (size_t)(t0+16)*32);
        compute16(bA, lw_i, hn, hp + t0, lane);
        int t2 = (bp < 63) ? (t0 + 32) : 0;      // last iter: dummy reload of blk 0
        load_bank(bA, src + (size_t)t2*32);
        compute16(bB, lw_i, hn, hp + t0 + 16, lane);
    }
}

// ---------------- y = repeat(hsT,128) + res (bf16) -------------------------
__global__ __launch_bounds__(256) void y_assemble(
    const float* __restrict__ hsT, const unsigned short* __restrict__ xr,
    unsigned short* __restrict__ y)
{
    int idx = blockIdx.x*256 + threadIdx.x;
    int r = idx >> 10;
    int c2 = (idx & 1023)*2;
    int bb = r >> 11, s = r & (SEQ-1);
    unsigned int u = *(const unsigned int*)(xr + (size_t)r*DFF + DINNER + c2);
    float h0 = hsT[(size_t)(bb*16 + (c2 >> 7))*SEQ + s];
    float y0 = h0 + b2f(u & 0xffff);
    float y1 = h0 + b2f(u >> 16);
    *(unsigned int*)(y + (size_t)r*DINNER + c2) =
        (unsigned int)f2b(y0) | ((unsigned int)f2b(y1) << 16);
}

// ---------------------------------------------------------------------------
extern "C" void kernel_launch(void* const* d_in, const int* in_sizes, int n_in,
                              void* d_out, int out_size, void* d_ws, size_t ws_size,
                              hipStream_t stream)
{
    (void)in_sizes; (void)n_in; (void)out_size; (void)ws_size;
    const float* x     = (const float*)d_in[0];
    const float* ln1_g = (const float*)d_in[1];
    const float* ln1_b = (const float*)d_in[2];
    const float* Wq    = (const float*)d_in[3];
    const float* bq    = (const float*)d_in[4];
    const float* Wk    = (const float*)d_in[5];
    const float* bk    = (const float*)d_in[6];
    const float* Wv    = (const float*)d_in[7];
    const float* bv    = (const float*)d_in[8];
    const float* Wo    = (const float*)d_in[9];
    const float* bo    = (const float*)d_in[10];
    const float* ln2_g = (const float*)d_in[11];
    const float* ln2_b = (const float*)d_in[12];
    const float* in_w  = (const float*)d_in[13];
    const float* in_b  = (const float*)d_in[14];
    const float* conv_w= (const float*)d_in[15];
    const float* conv_b= (const float*)d_in[16];
    const float* xp_w  = (const float*)d_in[17];
    const float* xp_b  = (const float*)d_in[18];
    const float* dt    = (const float*)d_in[19];
    const float* A     = (const float*)d_in[20];
    const float* out_w = (const float*)d_in[22];
    const float* out_b = (const float*)d_in[23];
    const float* ln3_g = (const float*)d_in[24];
    const float* ln3_b = (const float*)d_in[25];
    const float* fc1_w = (const float*)d_in[26];
    const float* fc1_b = (const float*)d_in[27];
    const float* fc2_w = (const float*)d_in[28];
    const float* fc2_b = (const float*)d_in[29];

    char* ws = (char*)d_ws;
    const size_t MB = 1ull << 20;
    unsigned short* qkvT = (unsigned short*)(ws + 0*MB);   // WqT|WkT|WvT, 6MB
    unsigned short* WoT  = (unsigned short*)(ws + 6*MB);
    unsigned short* inT  = (unsigned short*)(ws + 8*MB);
    unsigned short* outT = (unsigned short*)(ws + 16*MB);
    unsigned short* f1T  = (unsigned short*)(ws + 20*MB);
    unsigned short* f2T  = (unsigned short*)(ws + 28*MB);
    unsigned short* hbf  = (unsigned short*)(ws + 36*MB);  // also vT window
    float*          x2   = (float*)(ws + 44*MB);
    float*          x3   = (float*)(ws + 60*MB);
    unsigned short* qkv  = (unsigned short*)(ws + 76*MB);  // 24MB fused QKV
    unsigned short* attnb= (unsigned short*)(ws + 100*MB);
    unsigned short* xr   = (unsigned short*)(ws + 76*MB);  // reuse after attn
    unsigned short* ffn  = (unsigned short*)(ws + 76*MB);  // reuse after y
    unsigned short* xm2  = (unsigned short*)(ws + 108*MB);
    unsigned short* yb   = (unsigned short*)(ws + 108*MB); // reuse after xp
    float*          xdbl = (float*)(ws + 124*MB);
    float*          hsb  = (float*)(ws + 124*MB + 512*1024);
    float*          bqkv = (float*)(ws + 125*MB);

    dim3 blk(256);
    transpose_cast4<<<dim3(16,16,4), blk, 0, stream>>>(
        Wq, Wk, Wv, Wo,
        qkvT, qkvT + 1024*1024, qkvT + 2*1024*1024, WoT, 1024, 1024);
    transpose_cast2<<<dim3(64,16,2), blk, 0, stream>>>(in_w, fc1_w, inT, f1T, 1024, 4096);
    transpose_cast<<<dim3(16,32), blk, 0, stream>>>(out_w, outT, 2048, 1024);
    transpose_cast<<<dim3(16,64), blk, 0, stream>>>(fc2_w, f2T, 4096, 1024);
    concat_bias<<<12, blk, 0, stream>>>(bq, bk, bv, bqkv);

    layernorm_bf16<<<MROWS, blk, 0, stream>>>(x, ln1_g, ln1_b, hbf);
    gemm_bt<128,1,0,0><<<dim3(24,32), blk, 0, stream>>>(hbf, qkvT, bqkv, nullptr, qkv, QKVLD, 1024);
    transpose_v<<<dim3(32,32), blk, 0, stream>>>(qkv, hbf);   // vT in hbf window
    attn_flash<<<dim3(16,32), blk, 0, stream>>>(qkv, hbf, attnb);
    gemm_bt<64,0,1,0><<<dim3(16,32), blk, 0, stream>>>(attnb, WoT, bo, x, x2, 1024, 1024);
    layernorm_bf16<<<MROWS, blk, 0, stream>>>(x2, ln2_g, ln2_b, hbf);
    gemm_bt<128,1,0,0><<<dim3(32,32), blk, 0, stream>>>(hbf, inT, in_b, nullptr, xr, 4096, 1024);
    conv_silu<<<16384, blk, 0, stream>>>(xr, conv_w, conv_b, xm2);
    xp_gemm<<<512, blk, 0, stream>>>(xm2, xp_w, xp_b, xdbl);
    scan_k<<<1, dim3(128), 0, stream>>>(xdbl, dt, A, hsb);
    y_assemble<<<16384, blk, 0, stream>>>(hsb, xr, yb);
    gemm_bt<64,0,1,0><<<dim3(16,32), blk, 0, stream>>>(yb, outT, out_b, x2, x3, 1024, 2048);
    layernorm_bf16<<<MROWS, blk, 0, stream>>>(x3, ln3_g, ln3_b, hbf);
    gemm_bt<128,1,0,1><<<dim3(32,32), blk, 0, stream>>>(hbf, f1T, fc1_b, nullptr, ffn, 4096, 1024);
    gemm_bt<64,0,1,0><<<dim3(16,32), blk, 0, stream>>>(ffn, f2T, fc2_b, x3, (float*)d_out, 1024, 4096);
}